// Round 1
// baseline (4419.937 us; speedup 1.0000x reference)
//
#include <hip/hip_runtime.h>
#include <cmath>

#define BATCH 8
#define CIN   64
#define HH    128
#define WW    128
#define COUT  64
#define KKT   9     // K*K taps
#define NOFF  18    // 2*K*K offset channels
#define PIX   16    // pixels per block (one row segment)

__global__ __launch_bounds__(256)
void deform_fused(const float* __restrict__ x,
                  const float* __restrict__ w_off,
                  const float* __restrict__ b_off,
                  const float* __restrict__ w_dcn,
                  float* __restrict__ out) {
    __shared__ float s_off[PIX][NOFF];          // offset conv results
    __shared__ int   s_y0[PIX][KKT];
    __shared__ int   s_x0[PIX][KKT];
    __shared__ float s_bw[PIX][KKT][4];         // bilinear corner weights
    __shared__ float s_vals[PIX][CIN * KKT];    // sampled values [p][ci*9+kk]

    const int blk   = blockIdx.x;
    const int wtile = blk % (WW / PIX);
    const int ho    = (blk / (WW / PIX)) % HH;
    const int b     = blk / ((WW / PIX) * HH);
    const int wbase = wtile * PIX;
    const int tid   = threadIdx.x;

    const float* __restrict__ xb = x + (size_t)b * CIN * HH * WW;

    // ---- Step 1: offset conv (18 channels) for the 16 pixels ----
    for (int t = tid; t < PIX * NOFF; t += 256) {
        const int p  = t / NOFF;
        const int oc = t % NOFF;
        const int wo = wbase + p;
        float acc = b_off[oc];
        for (int ci = 0; ci < CIN; ++ci) {
            const float* __restrict__ xc = xb + ci * HH * WW;
            const float* __restrict__ wr = w_off + ((size_t)oc * CIN + ci) * 9;
            #pragma unroll
            for (int ky = 0; ky < 3; ++ky) {
                const int y = ho + ky - 1;
                if (y < 0 || y >= HH) continue;
                #pragma unroll
                for (int kx = 0; kx < 3; ++kx) {
                    const int xx = wo + kx - 1;
                    if (xx < 0 || xx >= WW) continue;
                    acc += xc[y * WW + xx] * wr[ky * 3 + kx];
                }
            }
        }
        s_off[p][oc] = acc;
    }
    __syncthreads();

    // ---- Step 2: sampling coords + bilinear weights per (pixel, tap) ----
    for (int t = tid; t < PIX * KKT; t += 256) {
        const int p  = t / KKT;
        const int kk = t % KKT;
        const int wo = wbase + p;
        const float py = (float)(ho - 1 + kk / 3) + s_off[p][2 * kk + 0];
        const float px = (float)(wo - 1 + kk % 3) + s_off[p][2 * kk + 1];
        const float fy = floorf(py);
        const float fx = floorf(px);
        const float dy = py - fy;
        const float dx = px - fx;
        s_y0[p][kk] = (int)fy;
        s_x0[p][kk] = (int)fx;
        s_bw[p][kk][0] = (1.f - dy) * (1.f - dx);
        s_bw[p][kk][1] = (1.f - dy) * dx;
        s_bw[p][kk][2] = dy * (1.f - dx);
        s_bw[p][kk][3] = dy * dx;
    }
    __syncthreads();

    // ---- Step 3: gather + bilinear interpolation into LDS ----
    for (int t = tid; t < PIX * KKT * CIN; t += 256) {
        const int p  = t / (KKT * CIN);
        const int r  = t % (KKT * CIN);
        const int kk = r / CIN;
        const int ci = r % CIN;
        const int y0 = s_y0[p][kk];
        const int x0 = s_x0[p][kk];
        const float* __restrict__ xc = xb + ci * HH * WW;
        float v = 0.f;
        {   // (y0, x0)
            if (y0 >= 0 && y0 < HH && x0 >= 0 && x0 < WW)
                v += xc[y0 * WW + x0] * s_bw[p][kk][0];
        }
        {   // (y0, x0+1)
            const int x1 = x0 + 1;
            if (y0 >= 0 && y0 < HH && x1 >= 0 && x1 < WW)
                v += xc[y0 * WW + x1] * s_bw[p][kk][1];
        }
        {   // (y0+1, x0)
            const int y1 = y0 + 1;
            if (y1 >= 0 && y1 < HH && x0 >= 0 && x0 < WW)
                v += xc[y1 * WW + x0] * s_bw[p][kk][2];
        }
        {   // (y0+1, x0+1)
            const int y1 = y0 + 1;
            const int x1 = x0 + 1;
            if (y1 >= 0 && y1 < HH && x1 >= 0 && x1 < WW)
                v += xc[y1 * WW + x1] * s_bw[p][kk][3];
        }
        s_vals[p][ci * KKT + kk] = v;   // layout matches w_dcn[o][ci][kk]
    }
    __syncthreads();

    // ---- Step 4: dot products. wave w handles pixels {w, w+4, w+8, w+12},
    //      lane = output channel. LDS reads are wave-uniform (broadcast). ----
    const int co = tid & 63;
    const int wv = tid >> 6;
    const float* __restrict__ wrow = w_dcn + (size_t)co * (CIN * KKT);
    float acc0 = 0.f, acc1 = 0.f, acc2 = 0.f, acc3 = 0.f;
    for (int j = 0; j < CIN * KKT; ++j) {
        const float wj = wrow[j];
        acc0 += s_vals[wv + 0][j] * wj;
        acc1 += s_vals[wv + 4][j] * wj;
        acc2 += s_vals[wv + 8][j] * wj;
        acc3 += s_vals[wv + 12][j] * wj;
    }
    const size_t obase = (((size_t)b * COUT + co) * HH + ho) * WW + wbase;
    out[obase + wv + 0]  = acc0;
    out[obase + wv + 4]  = acc1;
    out[obase + wv + 8]  = acc2;
    out[obase + wv + 12] = acc3;
}

extern "C" void kernel_launch(void* const* d_in, const int* in_sizes, int n_in,
                              void* d_out, int out_size, void* d_ws, size_t ws_size,
                              hipStream_t stream) {
    const float* x     = (const float*)d_in[0];
    const float* w_off = (const float*)d_in[1];
    const float* b_off = (const float*)d_in[2];
    const float* w_dcn = (const float*)d_in[3];
    float* out = (float*)d_out;

    const int nblocks = BATCH * HH * (WW / PIX);   // 8192
    deform_fused<<<nblocks, 256, 0, stream>>>(x, w_off, b_off, w_dcn, out);
}

// Round 2
// 3113.188 us; speedup vs baseline: 1.4197x; 1.4197x over previous
//
#include <hip/hip_runtime.h>
#include <cmath>

#define BATCH 8
#define CIN   64
#define HH    128
#define WW    128
#define COUT  64
#define KKT   9            // K*K taps
#define NOFF  18           // 2*K*K offset channels
#define PIX   16           // pixels per block (one row segment)
#define KTOT  (CIN * KKT)  // 576 = GEMM K
#define KB_N  (KTOT / 32)  // 18 K-chunks of 32
#define AP    584          // padded A row length in bf16 (576 + 8) -> 1168B stride, 292 dwords = 4 mod 32

typedef __bf16 bf16x8 __attribute__((ext_vector_type(8)));
typedef float  f32x4  __attribute__((ext_vector_type(4)));

// Weights pre-converted to bf16 in exact B-fragment order:
// [kb][wave][kgrp][n][e]  (lane l of wave w reads [kb][w][l>>4][l&15][0..7] -> 16B coalesced)
__device__ __bf16 g_wb[KB_N * 4 * 4 * 16 * 8];   // 36864 elems

__global__ __launch_bounds__(256)
void prep_wb(const float* __restrict__ w_dcn) {
    const int idx = blockIdx.x * 256 + threadIdx.x;   // 36864 total
    const int e   = idx & 7;
    const int n   = (idx >> 3) & 15;
    const int kg  = (idx >> 7) & 3;
    const int w   = (idx >> 9) & 3;
    const int kb  = idx >> 11;
    const int cout = w * 16 + n;
    const int k    = kb * 32 + kg * 8 + e;
    g_wb[idx] = (__bf16)w_dcn[cout * KTOT + k];
}

__global__ __launch_bounds__(256)
void deform_fused(const float* __restrict__ x,
                  const float* __restrict__ w_off,
                  const float* __restrict__ b_off,
                  float* __restrict__ out) {
    __shared__ float  s_off[PIX][NOFF];
    __shared__ int    s_y0[PIX][KKT];
    __shared__ int    s_x0[PIX][KKT];
    __shared__ float  s_bw[PIX][KKT][4];
    __shared__ __bf16 s_vals[PIX][AP];   // A operand: [pixel][ci*9+kk] bf16

    const int blk   = blockIdx.x;
    const int wtile = blk % (WW / PIX);
    const int ho    = (blk / (WW / PIX)) % HH;
    const int b     = blk / ((WW / PIX) * HH);
    const int wbase = wtile * PIX;
    const int tid   = threadIdx.x;

    const float* __restrict__ xb = x + (size_t)b * CIN * HH * WW;

    // ---- Step 1: offset conv (18 ch x 16 px), 4 interleaved accumulators ----
    for (int t = tid; t < PIX * NOFF; t += 256) {
        const int p  = t / NOFF;
        const int oc = t % NOFF;
        const int wo = wbase + p;
        const float* __restrict__ wr0 = w_off + (size_t)oc * CIN * 9;
        const int ym = (ho > 0), yp = (ho < HH - 1);
        const int xm = (wo > 0), xp = (wo < WW - 1);
        float a[4] = {0.f, 0.f, 0.f, 0.f};
        for (int ci = 0; ci < CIN; ci += 4) {
            #pragma unroll
            for (int q = 0; q < 4; ++q) {
                const float* __restrict__ xc = xb + (size_t)(ci + q) * HH * WW + ho * WW + wo;
                const float* __restrict__ wr = wr0 + (ci + q) * 9;
                float s = 0.f;
                if (ym) {
                    if (xm) s += xc[-WW - 1] * wr[0];
                    s += xc[-WW] * wr[1];
                    if (xp) s += xc[-WW + 1] * wr[2];
                }
                if (xm) s += xc[-1] * wr[3];
                s += xc[0] * wr[4];
                if (xp) s += xc[1] * wr[5];
                if (yp) {
                    if (xm) s += xc[WW - 1] * wr[6];
                    s += xc[WW] * wr[7];
                    if (xp) s += xc[WW + 1] * wr[8];
                }
                a[q] += s;
            }
        }
        s_off[p][oc] = (a[0] + a[1]) + (a[2] + a[3]) + b_off[oc];
    }
    __syncthreads();

    // ---- Step 2: sampling coords + bilinear corner weights ----
    for (int t = tid; t < PIX * KKT; t += 256) {
        const int p  = t / KKT;
        const int kk = t % KKT;
        const int wo = wbase + p;
        const float py = (float)(ho - 1 + kk / 3) + s_off[p][2 * kk + 0];
        const float px = (float)(wo - 1 + kk % 3) + s_off[p][2 * kk + 1];
        const float fy = floorf(py);
        const float fx = floorf(px);
        const float dy = py - fy;
        const float dx = px - fx;
        s_y0[p][kk] = (int)fy;
        s_x0[p][kk] = (int)fx;
        s_bw[p][kk][0] = (1.f - dy) * (1.f - dx);
        s_bw[p][kk][1] = (1.f - dy) * dx;
        s_bw[p][kk][2] = dy * (1.f - dx);
        s_bw[p][kk][3] = dy * dx;
    }
    __syncthreads();

    // ---- Step 3: gather + bilerp. Lanes vary (p,kk) at fixed ci -> coalesced-ish ----
    for (int t = tid; t < CIN * PIX * KKT; t += 256) {
        const int ci = t / (PIX * KKT);
        const int r  = t % (PIX * KKT);
        const int p  = r / KKT;
        const int kk = r % KKT;
        const int y0 = s_y0[p][kk];
        const int x0 = s_x0[p][kk];
        const float* __restrict__ xc = xb + (size_t)ci * HH * WW;
        const int y1 = y0 + 1, x1 = x0 + 1;
        float v = 0.f;
        if (y0 >= 0 && y0 < HH) {
            if (x0 >= 0 && x0 < WW) v += xc[y0 * WW + x0] * s_bw[p][kk][0];
            if (x1 >= 0 && x1 < WW) v += xc[y0 * WW + x1] * s_bw[p][kk][1];
        }
        if (y1 >= 0 && y1 < HH) {
            if (x0 >= 0 && x0 < WW) v += xc[y1 * WW + x0] * s_bw[p][kk][2];
            if (x1 >= 0 && x1 < WW) v += xc[y1 * WW + x1] * s_bw[p][kk][3];
        }
        s_vals[p][ci * KKT + kk] = (__bf16)v;
    }
    __syncthreads();

    // ---- Step 4: 16x64x576 GEMM via MFMA. wave w -> couts [16w, 16w+16) ----
    const int w  = tid >> 6;
    const int l  = tid & 63;
    const int lr = l & 15;        // A row (pixel) / B col (cout within wave)
    const int lg = l >> 4;        // k-group
    f32x4 acc = {0.f, 0.f, 0.f, 0.f};
    const __bf16* __restrict__ bsrc = g_wb + (((size_t)w * 4 + lg) * 16 + lr) * 8;
    #pragma unroll
    for (int kb = 0; kb < KB_N; ++kb) {
        bf16x8 afrag = *(const bf16x8*)(&s_vals[lr][kb * 32 + lg * 8]);
        bf16x8 bfrag = *(const bf16x8*)(bsrc + (size_t)kb * 2048);
        acc = __builtin_amdgcn_mfma_f32_16x16x32_bf16(afrag, bfrag, acc, 0, 0, 0);
    }
    // D: col(n)=lane&15 -> cout, row(m)=4*(lane>>4)+reg -> pixel
    const int cout = w * 16 + lr;
    const size_t obase = (((size_t)b * COUT + cout) * HH + ho) * WW + wbase + lg * 4;
    #pragma unroll
    for (int r = 0; r < 4; ++r) out[obase + r] = acc[r];
}

extern "C" void kernel_launch(void* const* d_in, const int* in_sizes, int n_in,
                              void* d_out, int out_size, void* d_ws, size_t ws_size,
                              hipStream_t stream) {
    const float* x     = (const float*)d_in[0];
    const float* w_off = (const float*)d_in[1];
    const float* b_off = (const float*)d_in[2];
    const float* w_dcn = (const float*)d_in[3];
    float* out = (float*)d_out;

    prep_wb<<<(KB_N * 4 * 4 * 16 * 8) / 256, 256, 0, stream>>>(w_dcn);

    const int nblocks = BATCH * HH * (WW / PIX);   // 8192
    deform_fused<<<nblocks, 256, 0, stream>>>(x, w_off, b_off, out);
}

// Round 3
// 316.260 us; speedup vs baseline: 13.9756x; 9.8438x over previous
//
#include <hip/hip_runtime.h>
#include <cmath>

#define BATCH 8
#define CIN   64
#define HH    128
#define WW    128
#define COUT  64
#define KKT   9            // K*K taps
#define NOFF  18           // 2*K*K offset channels
#define PIX   16           // pixels per block (one row segment)
#define KTOT  576          // GEMM K = CIN*KKT
#define KB_N  18           // K chunks of 32
#define AP    584          // padded s_vals row (bf16 elems)
#define WROWS 9            // window rows: ho-4 .. ho+4
#define WCOLS 24           // window cols: wbase-4 .. wbase+19
#define NSAMP (PIX*KKT)    // 144 samples per block

typedef __bf16 bf16x8 __attribute__((ext_vector_type(8)));
typedef float  f32x4  __attribute__((ext_vector_type(4)));

// Pre-packed bf16 weights in exact MFMA B-fragment order, tap-major K (k = kk*64+ci).
__device__ __bf16 g_wb[KB_N * 4 * 4 * 16 * 8];      // dcn:    [kb][wave4][lg][lr][e]
__device__ __bf16 g_wboff[KB_N * 2 * 4 * 16 * 8];   // offset: [kb][ntile2][lg][lr][e]

__global__ __launch_bounds__(256)
void prep_w(const float* __restrict__ w_dcn, const float* __restrict__ w_off) {
    const int idx = blockIdx.x * 256 + threadIdx.x;      // 55296 total
    if (idx < KB_N * 4 * 4 * 16 * 8) {                   // 36864: dcn weights
        const int e  = idx & 7;
        const int lr = (idx >> 3) & 15;
        const int lg = (idx >> 7) & 3;
        const int w  = (idx >> 9) & 3;
        const int kb = idx >> 11;
        const int cout = w * 16 + lr;
        const int k  = kb * 32 + lg * 8 + e;
        const int kk = k >> 6, ci = k & 63;
        g_wb[idx] = (__bf16)w_dcn[cout * KTOT + ci * KKT + kk];
    } else {                                             // 18432: offset-conv weights
        const int j  = idx - KB_N * 4 * 4 * 16 * 8;
        const int e  = j & 7;
        const int lr = (j >> 3) & 15;
        const int lg = (j >> 7) & 3;
        const int nt = (j >> 9) & 1;
        const int kb = j >> 10;
        const int oc = nt * 16 + lr;
        const int k  = kb * 32 + lg * 8 + e;
        const int kk = k >> 6, ci = k & 63;
        g_wboff[j] = (oc < NOFF) ? (__bf16)w_off[oc * KTOT + ci * KKT + kk] : (__bf16)0.f;
    }
}

__global__ __launch_bounds__(256)
void deform_fused(const float* __restrict__ x,
                  const float* __restrict__ b_off,
                  float* __restrict__ out) {
    // x window, layout [yr][xr][ci] bf16, XOR-swizzled: elem ^= (xr&7)<<3
    __shared__ __align__(16) __bf16 s_xw[WROWS * WCOLS * 64];    // 27648 B
    __shared__ __align__(16) __bf16 s_vals[PIX][AP];             // 18688 B (aliased as f32 reduce buf)
    __shared__ float s_off[PIX][NOFF];
    __shared__ int   s_y0[NSAMP];
    __shared__ int   s_x0[NSAMP];
    __shared__ float s_bw[NSAMP][4];
    __shared__ int   s_fast[NSAMP];

    const int blk   = blockIdx.x;
    const int wtile = blk % (WW / PIX);
    const int ho    = (blk / (WW / PIX)) % HH;
    const int b     = blk / ((WW / PIX) * HH);
    const int wbase = wtile * PIX;
    const int tid   = threadIdx.x;
    const int wid   = tid >> 6;
    const int lane  = tid & 63;
    const int lr    = lane & 15;
    const int lg    = lane >> 4;

    const float* __restrict__ xb = x + (size_t)b * CIN * HH * WW;

    // ---- Phase 1: stage x window (coalesced global, bf16 LDS) ----
    for (int t = tid; t < WROWS * WCOLS * 64; t += 256) {
        const int xr   = t % WCOLS;
        const int rest = t / WCOLS;
        const int yr   = rest % WROWS;
        const int ci   = rest / WROWS;
        const int y  = ho - 4 + yr;
        const int xc = wbase - 4 + xr;
        float v = 0.f;
        if (y >= 0 && y < HH && xc >= 0 && xc < WW)
            v = xb[(size_t)ci * HH * WW + y * WW + xc];
        const int elem = (((yr * WCOLS + xr) << 6) + ci) ^ ((xr & 7) << 3);
        s_xw[elem] = (__bf16)v;
    }
    __syncthreads();

    // ---- Phase 2: offset conv via MFMA (M=16 px, N=32 [18 used], K=576) ----
    {
        const int nt = wid >> 1;     // N-tile (oc/16)
        const int h  = wid & 1;      // K-half
        f32x4 acc = {0.f, 0.f, 0.f, 0.f};
        #pragma unroll
        for (int j = 0; j < 9; ++j) {
            const int kb    = h * 9 + j;
            const int kbase = kb * 32 + lg * 8;
            const int kk    = kbase >> 6;         // tap
            const int ci0   = kbase & 63;
            const int yr    = 3 + kk / 3;
            const int xr    = lr + 3 + kk % 3;
            const int elem  = (((yr * WCOLS + xr) << 6) + ci0) ^ ((xr & 7) << 3);
            bf16x8 a  = *(const bf16x8*)&s_xw[elem];
            bf16x8 bb = *(const bf16x8*)&g_wboff[(((kb * 2 + nt) * 4 + lg) * 16 + lr) * 8];
            acc = __builtin_amdgcn_mfma_f32_16x16x32_bf16(a, bb, acc, 0, 0, 0);
        }
        f32x4* s_red = (f32x4*)&s_vals[0][0];
        if (h == 1) s_red[nt * 64 + lane] = acc;
        __syncthreads();
        if (h == 0) {
            const int oc = nt * 16 + lr;          // C: col=lr -> oc, row=lg*4+r -> px
            if (oc < NOFF) {
                f32x4 o = s_red[nt * 64 + lane];
                const float bias = b_off[oc];
                #pragma unroll
                for (int r = 0; r < 4; ++r)
                    s_off[lg * 4 + r][oc] = acc[r] + o[r] + bias;
            }
        }
    }
    __syncthreads();

    // ---- Phase 3: sampling coords + bilinear weights + fast-path flag ----
    if (tid < NSAMP) {
        const int p  = tid / KKT;
        const int kk = tid % KKT;
        const int wo = wbase + p;
        const float py = (float)(ho - 1 + kk / 3) + s_off[p][2 * kk + 0];
        const float px = (float)(wo - 1 + kk % 3) + s_off[p][2 * kk + 1];
        const float fy = floorf(py);
        const float fx = floorf(px);
        const int y0 = (int)fy;
        const int x0 = (int)fx;
        const float dy = py - fy, dx = px - fx;
        s_y0[tid] = y0;
        s_x0[tid] = x0;
        s_bw[tid][0] = (1.f - dy) * (1.f - dx);
        s_bw[tid][1] = (1.f - dy) * dx;
        s_bw[tid][2] = dy * (1.f - dx);
        s_bw[tid][3] = dy * dx;
        s_fast[tid] = (y0 >= ho - 4) & (y0 <= ho + 3) &
                      (x0 >= wbase - 4) & (x0 <= wbase + 18);
    }
    __syncthreads();

    // ---- Phase 4: bilinear sampling from LDS window (lane = ci, wave-uniform sample) ----
    for (int t = tid; t < NSAMP * 64; t += 256) {
        const int s  = t >> 6;        // sample = p*9+kk (wave-uniform)
        const int ci = t & 63;        // = lane
        const int p  = s / KKT;
        const int kk = s - p * KKT;
        const int y0 = s_y0[s], x0 = s_x0[s];
        const float w0 = s_bw[s][0], w1 = s_bw[s][1], w2 = s_bw[s][2], w3 = s_bw[s][3];
        float v;
        if (s_fast[s]) {
            const int yr = y0 - (ho - 4);
            const int xr = x0 - (wbase - 4);
            const int b0 = ((yr * WCOLS + xr) << 6) + ci;
            const int b1 = ((yr * WCOLS + xr + 1) << 6) + ci;
            const int sw0 = (xr & 7) << 3;
            const int sw1 = ((xr + 1) & 7) << 3;
            const float c00 = (float)s_xw[b0 ^ sw0];
            const float c01 = (float)s_xw[b1 ^ sw1];
            const float c10 = (float)s_xw[(b0 + (WCOLS << 6)) ^ sw0];
            const float c11 = (float)s_xw[(b1 + (WCOLS << 6)) ^ sw1];
            v = c00 * w0 + c01 * w1 + c10 * w2 + c11 * w3;
        } else {
            const float* __restrict__ xc = xb + (size_t)ci * HH * WW;
            const int y1 = y0 + 1, x1 = x0 + 1;
            v = 0.f;
            if (y0 >= 0 && y0 < HH) {
                if (x0 >= 0 && x0 < WW) v += xc[y0 * WW + x0] * w0;
                if (x1 >= 0 && x1 < WW) v += xc[y0 * WW + x1] * w1;
            }
            if (y1 >= 0 && y1 < HH) {
                if (x0 >= 0 && x0 < WW) v += xc[y1 * WW + x0] * w2;
                if (x1 >= 0 && x1 < WW) v += xc[y1 * WW + x1] * w3;
            }
        }
        s_vals[p][kk * 64 + ci] = (__bf16)v;
    }
    __syncthreads();

    // ---- Phase 5: 16x64x576 GEMM via MFMA, wave w -> couts [16w,16w+16) ----
    f32x4 acc = {0.f, 0.f, 0.f, 0.f};
    const __bf16* __restrict__ bsrc = g_wb + (((size_t)wid * 4 + lg) * 16 + lr) * 8;
    #pragma unroll
    for (int kb = 0; kb < KB_N; ++kb) {
        bf16x8 afrag = *(const bf16x8*)&s_vals[lr][kb * 32 + lg * 8];
        bf16x8 bfrag = *(const bf16x8*)(bsrc + (size_t)kb * 2048);
        acc = __builtin_amdgcn_mfma_f32_16x16x32_bf16(afrag, bfrag, acc, 0, 0, 0);
    }
    const int cout = wid * 16 + lr;
    const size_t obase = (((size_t)b * COUT + cout) * HH + ho) * WW + wbase + lg * 4;
    #pragma unroll
    for (int r = 0; r < 4; ++r) out[obase + r] = acc[r];
}

extern "C" void kernel_launch(void* const* d_in, const int* in_sizes, int n_in,
                              void* d_out, int out_size, void* d_ws, size_t ws_size,
                              hipStream_t stream) {
    const float* x     = (const float*)d_in[0];
    const float* w_off = (const float*)d_in[1];
    const float* b_off = (const float*)d_in[2];
    const float* w_dcn = (const float*)d_in[3];
    float* out = (float*)d_out;

    prep_w<<<216, 256, 0, stream>>>(w_dcn, w_off);

    const int nblocks = BATCH * HH * (WW / PIX);   // 8192
    deform_fused<<<nblocks, 256, 0, stream>>>(x, b_off, out);
}

// Round 4
// 103.229 us; speedup vs baseline: 42.8166x; 3.0637x over previous
//
#include <hip/hip_runtime.h>
#include <cmath>

#define BATCH 8
#define CIN   64
#define HH    128
#define WW    128
#define COUT  64
#define KKT   9            // K*K taps
#define NOFF  18           // 2*K*K offset channels
#define PIX   16           // pixels per block (one row segment)
#define KTOT  576          // GEMM K = CIN*KKT (tap-major: k = kk*64+ci)
#define KB_N  18           // K chunks of 32
#define WROWS 5            // window rows: ho-2 .. ho+2
#define WCOLS 24           // window cols: wbase-4 .. wbase+19 (16B-aligned chunks)
#define NSAMP (PIX*KKT)    // 144 samples per block

typedef __bf16 bf16x8 __attribute__((ext_vector_type(8)));
typedef float  f32x4  __attribute__((ext_vector_type(4)));

// Pre-packed bf16 weights in exact MFMA B-fragment order, tap-major K.
__device__ __bf16 g_wb[KB_N * 4 * 4 * 16 * 8];      // dcn:    [kb][wave4][lg][lr][e]
__device__ __bf16 g_wboff[KB_N * 2 * 4 * 16 * 8];   // offset: [kb][ntile2][lg][lr][e]

__global__ __launch_bounds__(256)
void prep_w(const float* __restrict__ w_dcn, const float* __restrict__ w_off) {
    const int idx = blockIdx.x * 256 + threadIdx.x;      // 55296 total
    if (idx < KB_N * 4 * 4 * 16 * 8) {                   // 36864: dcn weights
        const int e  = idx & 7;
        const int lr = (idx >> 3) & 15;
        const int lg = (idx >> 7) & 3;
        const int w  = (idx >> 9) & 3;
        const int kb = idx >> 11;
        const int cout = w * 16 + lr;
        const int k  = kb * 32 + lg * 8 + e;
        const int kk = k >> 6, ci = k & 63;
        g_wb[idx] = (__bf16)w_dcn[cout * KTOT + ci * KKT + kk];
    } else {                                             // 18432: offset-conv weights
        const int j  = idx - KB_N * 4 * 4 * 16 * 8;
        const int e  = j & 7;
        const int lr = (j >> 3) & 15;
        const int lg = (j >> 7) & 3;
        const int nt = (j >> 9) & 1;
        const int kb = j >> 10;
        const int oc = nt * 16 + lr;
        const int k  = kb * 32 + lg * 8 + e;
        const int kk = k >> 6, ci = k & 63;
        g_wboff[j] = (oc < NOFF) ? (__bf16)w_off[oc * KTOT + ci * KKT + kk] : (__bf16)0.f;
    }
}

__global__ __launch_bounds__(256)
void deform_fused(const float* __restrict__ x,
                  const float* __restrict__ b_off,
                  float* __restrict__ out) {
    // x window [yr][xr][ci] bf16, XOR-swizzled at 16B: elem ^= (xr&7)<<3
    __shared__ __align__(16) __bf16 s_xw[WROWS * WCOLS * 64];   // 15360 B
    // A operand [p][k], XOR-swizzled: elem_in_row ^= (p&7)<<3. Also aliases
    // the phase-2 reduce buffer (bytes 0..2047) and s_off (bytes 2048..3199).
    __shared__ __align__(16) __bf16 s_vals[PIX * KTOT];         // 18432 B
    __shared__ int   s_yx[NSAMP];        // (y0<<16)|(x0&0xffff)
    __shared__ float s_bw[NSAMP][4];     // bilinear corner weights
    __shared__ int   s_fast[NSAMP];

    const int blk   = blockIdx.x;
    const int wtile = blk % (WW / PIX);
    const int ho    = (blk / (WW / PIX)) % HH;
    const int b     = blk / ((WW / PIX) * HH);
    const int wbase = wtile * PIX;
    const int tid   = threadIdx.x;
    const int wid   = tid >> 6;
    const int lane  = tid & 63;
    const int lr    = lane & 15;
    const int lg    = lane >> 4;

    const float* __restrict__ xb = x + (size_t)b * CIN * HH * WW;

    // ---- Phase 1: stage x window (aligned float4 global, swizzled bf16 LDS) ----
    for (int t = tid; t < 64 * WROWS * (WCOLS / 4); t += 256) {   // 1920 tasks
        const int c  = t % (WCOLS / 4);
        const int yr = (t / (WCOLS / 4)) % WROWS;
        const int ci = t / ((WCOLS / 4) * WROWS);
        const int y  = ho - 2 + yr;
        const int xs = wbase - 4 + c * 4;
        float v0 = 0.f, v1 = 0.f, v2 = 0.f, v3 = 0.f;
        if (y >= 0 && y < HH) {
            const float* __restrict__ rp = xb + (size_t)ci * (HH * WW) + y * WW + xs;
            if (xs >= 0 && xs <= WW - 4) {
                const f32x4 v = *(const f32x4*)rp;   // 16B-aligned (wbase%16==0)
                v0 = v[0]; v1 = v[1]; v2 = v[2]; v3 = v[3];
            } else {
                if (xs + 0 >= 0 && xs + 0 < WW) v0 = rp[0];
                if (xs + 1 >= 0 && xs + 1 < WW) v1 = rp[1];
                if (xs + 2 >= 0 && xs + 2 < WW) v2 = rp[2];
                if (xs + 3 >= 0 && xs + 3 < WW) v3 = rp[3];
            }
        }
        const int eb = ((yr * WCOLS + c * 4) << 6) + ci;
        s_xw[(eb + 0 * 64) ^ (((c * 4 + 0) & 7) << 3)] = (__bf16)v0;
        s_xw[(eb + 1 * 64) ^ (((c * 4 + 1) & 7) << 3)] = (__bf16)v1;
        s_xw[(eb + 2 * 64) ^ (((c * 4 + 2) & 7) << 3)] = (__bf16)v2;
        s_xw[(eb + 3 * 64) ^ (((c * 4 + 3) & 7) << 3)] = (__bf16)v3;
    }
    __syncthreads();

    // ---- Phase 2: offset conv via MFMA (M=16 px, N=32 [18 used], K=576 split 2 ways) ----
    {
        const int nt = wid >> 1;     // oc tile
        const int h  = wid & 1;      // K half
        f32x4 acc = {0.f, 0.f, 0.f, 0.f};
        #pragma unroll
        for (int j = 0; j < 9; ++j) {
            const int kb    = h * 9 + j;
            const int kbase = kb * 32 + lg * 8;
            const int kk    = kbase >> 6;
            const int ci0   = kbase & 63;
            const int yr    = kk / 3 + 1;
            const int xr    = lr + kk % 3 + 3;
            const int elem  = (((yr * WCOLS + xr) << 6) + ci0) ^ ((xr & 7) << 3);
            bf16x8 a  = *(const bf16x8*)&s_xw[elem];
            bf16x8 bb = *(const bf16x8*)&g_wboff[(((kb * 2 + nt) * 4 + lg) * 16 + lr) * 8];
            acc = __builtin_amdgcn_mfma_f32_16x16x32_bf16(a, bb, acc, 0, 0, 0);
        }
        f32x4* s_red = (f32x4*)&s_vals[0];
        if (h == 1) s_red[nt * 64 + lane] = acc;
        __syncthreads();
        float* s_off = (float*)&s_vals[0] + 512;   // bytes 2048..3199
        if (h == 0) {
            const int oc = nt * 16 + lr;           // C: col=lr->oc, row=lg*4+r->px
            if (oc < NOFF) {
                const f32x4 o = s_red[nt * 64 + lane];
                const float bias = b_off[oc];
                #pragma unroll
                for (int r = 0; r < 4; ++r)
                    s_off[(lg * 4 + r) * NOFF + oc] = acc[r] + o[r] + bias;
            }
        }
    }
    __syncthreads();

    // ---- Phase 3: sampling coords + bilinear weights + fast flag ----
    if (tid < NSAMP) {
        const float* s_off = (const float*)&s_vals[0] + 512;
        const int p  = tid / KKT;
        const int kk = tid - p * KKT;
        const int wo = wbase + p;
        const float py = (float)(ho - 1 + kk / 3) + s_off[p * NOFF + 2 * kk + 0];
        const float px = (float)(wo - 1 + kk % 3) + s_off[p * NOFF + 2 * kk + 1];
        const float fy = floorf(py);
        const float fx = floorf(px);
        const int y0 = (int)fy;
        const int x0 = (int)fx;
        const float dy = py - fy, dx = px - fx;
        s_yx[tid] = (y0 << 16) | (x0 & 0xffff);
        s_bw[tid][0] = (1.f - dy) * (1.f - dx);
        s_bw[tid][1] = (1.f - dy) * dx;
        s_bw[tid][2] = dy * (1.f - dx);
        s_bw[tid][3] = dy * dx;
        s_fast[tid] = (y0 >= ho - 2) & (y0 <= ho + 1) &
                      (x0 >= wbase - 4) & (x0 <= wbase + 18);
    }
    __syncthreads();

    // ---- Phase 4: bilinear sampling, 8 channels per lane (b128 LDS ops) ----
    for (int t = tid; t < NSAMP * 8; t += 256) {
        const int s  = t >> 3;
        const int c8 = (t & 7) << 3;
        const int p  = s / KKT;
        const int kk = s - p * KKT;
        const int yx = s_yx[s];
        const int y0 = yx >> 16;
        const int x0 = (int)(short)(yx & 0xffff);
        const f32x4 w = *(const f32x4*)&s_bw[s][0];
        bf16x8 o;
        if (s_fast[s]) {
            const int yr  = y0 - (ho - 2);
            const int xr  = x0 - (wbase - 4);
            const int e00 = ((yr * WCOLS + xr) << 6) + c8;
            const int sw0 = (xr & 7) << 3;
            const int sw1 = ((xr + 1) & 7) << 3;
            const bf16x8 c00 = *(const bf16x8*)&s_xw[e00 ^ sw0];
            const bf16x8 c01 = *(const bf16x8*)&s_xw[(e00 + 64) ^ sw1];
            const bf16x8 c10 = *(const bf16x8*)&s_xw[(e00 + WCOLS * 64) ^ sw0];
            const bf16x8 c11 = *(const bf16x8*)&s_xw[(e00 + (WCOLS + 1) * 64) ^ sw1];
            #pragma unroll
            for (int e = 0; e < 8; ++e)
                o[e] = (__bf16)((float)c00[e] * w[0] + (float)c01[e] * w[1] +
                                (float)c10[e] * w[2] + (float)c11[e] * w[3]);
        } else {
            const int y1 = y0 + 1, x1 = x0 + 1;
            #pragma unroll
            for (int e = 0; e < 8; ++e) {
                const float* __restrict__ xc = xb + (size_t)(c8 + e) * (HH * WW);
                float v = 0.f;
                if (y0 >= 0 && y0 < HH) {
                    if (x0 >= 0 && x0 < WW) v += xc[y0 * WW + x0] * w[0];
                    if (x1 >= 0 && x1 < WW) v += xc[y0 * WW + x1] * w[1];
                }
                if (y1 >= 0 && y1 < HH) {
                    if (x0 >= 0 && x0 < WW) v += xc[y1 * WW + x0] * w[2];
                    if (x1 >= 0 && x1 < WW) v += xc[y1 * WW + x1] * w[3];
                }
                o[e] = (__bf16)v;
            }
        }
        const int ew = (kk * 64 + c8) ^ ((p & 7) << 3);
        *(bf16x8*)&s_vals[p * KTOT + ew] = o;
    }
    __syncthreads();

    // ---- Phase 5: 16x64x576 GEMM via MFMA, wave wid -> couts [16*wid, 16*wid+16) ----
    f32x4 acc = {0.f, 0.f, 0.f, 0.f};
    const __bf16* __restrict__ bsrc = g_wb + (((size_t)wid * 4 + lg) * 16 + lr) * 8;
    #pragma unroll
    for (int kb = 0; kb < KB_N; ++kb) {
        const int ew = (kb * 32 + lg * 8) ^ ((lr & 7) << 3);
        bf16x8 afrag = *(const bf16x8*)&s_vals[lr * KTOT + ew];
        bf16x8 bfrag = *(const bf16x8*)(bsrc + (size_t)kb * 2048);
        acc = __builtin_amdgcn_mfma_f32_16x16x32_bf16(afrag, bfrag, acc, 0, 0, 0);
    }
    const int cout = wid * 16 + lr;
    const size_t obase = (((size_t)b * COUT + cout) * HH + ho) * WW + wbase + lg * 4;
    *(f32x4*)&out[obase] = acc;
}

extern "C" void kernel_launch(void* const* d_in, const int* in_sizes, int n_in,
                              void* d_out, int out_size, void* d_ws, size_t ws_size,
                              hipStream_t stream) {
    const float* x     = (const float*)d_in[0];
    const float* w_off = (const float*)d_in[1];
    const float* b_off = (const float*)d_in[2];
    const float* w_dcn = (const float*)d_in[3];
    float* out = (float*)d_out;

    prep_w<<<216, 256, 0, stream>>>(w_dcn, w_off);

    const int nblocks = BATCH * HH * (WW / PIX);   // 8192
    deform_fused<<<nblocks, 256, 0, stream>>>(x, b_off, out);
}

// Round 8
// 101.680 us; speedup vs baseline: 43.4689x; 1.0152x over previous
//
#include <hip/hip_runtime.h>
#include <cmath>

#define BATCH 8
#define CIN   64
#define HH    128
#define WW    128
#define COUT  64
#define KKT   9            // K*K taps
#define NOFF  18           // 2*K*K offset channels
#define PIX   16           // pixels per block (one row segment)
#define KTOT  576          // GEMM K (tap-major: k = kk*64+ci)
#define KB_N  18           // K chunks of 32
#define WROWS 5            // window rows: ho-2 .. ho+2
#define WCOLS 24           // window cols: wbase-4 .. wbase+19
#define NSAMP (PIX*KKT)    // 144

typedef __bf16 bf16x8 __attribute__((ext_vector_type(8)));
typedef float  f32x4  __attribute__((ext_vector_type(4)));
typedef float  f32x2  __attribute__((ext_vector_type(2)));
typedef unsigned int u32;
typedef u32    u32x4  __attribute__((ext_vector_type(4)));

// Pre-packed bf16 weights in exact MFMA B-fragment order, tap-major K.
__device__ __bf16 g_wb[KB_N * 4 * 4 * 16 * 8];      // dcn:    [kb][wave4][lg][lr][e]
__device__ __bf16 g_wboff[KB_N * 2 * 4 * 16 * 8];   // offset: [kb][ntile2][lg][lr][e]

__global__ __launch_bounds__(256)
void prep_w(const float* __restrict__ w_dcn, const float* __restrict__ w_off) {
    const int idx = blockIdx.x * 256 + threadIdx.x;      // 55296 total
    if (idx < KB_N * 4 * 4 * 16 * 8) {
        const int e  = idx & 7;
        const int lr = (idx >> 3) & 15;
        const int lg = (idx >> 7) & 3;
        const int w  = (idx >> 9) & 3;
        const int kb = idx >> 11;
        const int cout = w * 16 + lr;
        const int k  = kb * 32 + lg * 8 + e;
        const int kk = k >> 6, ci = k & 63;
        g_wb[idx] = (__bf16)w_dcn[cout * KTOT + ci * KKT + kk];
    } else {
        const int j  = idx - KB_N * 4 * 4 * 16 * 8;
        const int e  = j & 7;
        const int lr = (j >> 3) & 15;
        const int lg = (j >> 7) & 3;
        const int nt = (j >> 9) & 1;
        const int kb = j >> 10;
        const int oc = nt * 16 + lr;
        const int k  = kb * 32 + lg * 8 + e;
        const int kk = k >> 6, ci = k & 63;
        g_wboff[j] = (oc < NOFF) ? (__bf16)w_off[oc * KTOT + ci * KKT + kk] : (__bf16)0.f;
    }
}

// exact bf16-pair -> f32x2 unpack (bit ops, no cvt)
static __device__ __forceinline__ f32x2 unpk(u32 v) {
    f32x2 r;
    r.x = __builtin_bit_cast(float, v << 16);
    r.y = __builtin_bit_cast(float, v & 0xffff0000u);
    return r;
}

__global__ __launch_bounds__(256)
void deform_fused(const float* __restrict__ x,
                  const float* __restrict__ b_off,
                  float* __restrict__ out) {
    // x window [yr][xr][ci] bf16, XOR-swizzled: elem ^= (xr&7)<<3
    __shared__ __align__(16) __bf16 s_xw[WROWS * WCOLS * 64];   // 15360 B
    // A operand [p][k], XOR-swizzled: col ^= (p&7)<<3. Aliased:
    // bytes [0,2048) = phase-2 reduce buf; bytes [2048,3200) = s_off.
    __shared__ __align__(16) __bf16 s_vals[PIX * KTOT];         // 18432 B
    __shared__ int   s_yx[NSAMP];        // (y0<<16)|(x0&0xffff)
    __shared__ float s_bw[NSAMP][4];     // bilinear corner weights
    __shared__ int   s_fast[NSAMP];

    const int blk   = blockIdx.x;
    const int wtile = blk % (WW / PIX);
    const int ho    = (blk / (WW / PIX)) % HH;
    const int b     = blk / ((WW / PIX) * HH);
    const int wbase = wtile * PIX;
    const int tid   = threadIdx.x;
    const int wid   = tid >> 6;
    const int lane  = tid & 63;
    const int lr    = lane & 15;
    const int lg    = lane >> 4;

    const float* __restrict__ xb = x + (size_t)b * CIN * HH * WW;
    const bool interior = (ho >= 2) & (ho <= HH - 3) & (wtile >= 1) & (wtile <= (WW / PIX) - 2);

    // ---- Phase 1: stage x window (round-4 addressing; interior skips guards) ----
    for (int t = tid; t < 64 * WROWS * (WCOLS / 4); t += 256) {   // 1920 tasks
        const int c  = t % (WCOLS / 4);
        const int yr = (t / (WCOLS / 4)) % WROWS;
        const int ci = t / ((WCOLS / 4) * WROWS);
        const int y  = ho - 2 + yr;
        const int xs = wbase - 4 + c * 4;
        float v0 = 0.f, v1 = 0.f, v2 = 0.f, v3 = 0.f;
        if (interior) {
            const float* __restrict__ rp = xb + (size_t)ci * (HH * WW) + y * WW + xs;
            const f32x4 v = *(const f32x4*)rp;   // 16B-aligned (wbase%16==0)
            v0 = v[0]; v1 = v[1]; v2 = v[2]; v3 = v[3];
        } else if (y >= 0 && y < HH) {
            const float* __restrict__ rp = xb + (size_t)ci * (HH * WW) + y * WW + xs;
            if (xs >= 0 && xs <= WW - 4) {
                const f32x4 v = *(const f32x4*)rp;
                v0 = v[0]; v1 = v[1]; v2 = v[2]; v3 = v[3];
            } else {
                if (xs + 0 >= 0 && xs + 0 < WW) v0 = rp[0];
                if (xs + 1 >= 0 && xs + 1 < WW) v1 = rp[1];
                if (xs + 2 >= 0 && xs + 2 < WW) v2 = rp[2];
                if (xs + 3 >= 0 && xs + 3 < WW) v3 = rp[3];
            }
        }
        const int eb = ((yr * WCOLS + c * 4) << 6) + ci;
        s_xw[(eb + 0 * 64) ^ (((c * 4 + 0) & 7) << 3)] = (__bf16)v0;
        s_xw[(eb + 1 * 64) ^ (((c * 4 + 1) & 7) << 3)] = (__bf16)v1;
        s_xw[(eb + 2 * 64) ^ (((c * 4 + 2) & 7) << 3)] = (__bf16)v2;
        s_xw[(eb + 3 * 64) ^ (((c * 4 + 3) & 7) << 3)] = (__bf16)v3;
    }
    __syncthreads();

    // ---- Phase 2: offset conv via MFMA bf16 (M=16, N=32[18 used], K=576 split 2) ----
    {
        const int nt = wid >> 1;
        const int h  = wid & 1;
        f32x4 acc = {0.f, 0.f, 0.f, 0.f};
        #pragma unroll
        for (int j = 0; j < 9; ++j) {
            const int kb    = h * 9 + j;
            const int kbase = kb * 32 + lg * 8;
            const int kk    = kbase >> 6;
            const int ci0   = kbase & 63;
            const int yr    = kk / 3 + 1;
            const int xr    = lr + kk % 3 + 3;
            const int elem  = (((yr * WCOLS + xr) << 6) + ci0) ^ ((xr & 7) << 3);
            const bf16x8 a  = *(const bf16x8*)&s_xw[elem];
            const bf16x8 bb = *(const bf16x8*)&g_wboff[(((kb * 2 + nt) * 4 + lg) * 16 + lr) * 8];
            acc = __builtin_amdgcn_mfma_f32_16x16x32_bf16(a, bb, acc, 0, 0, 0);
        }
        f32x4* s_red = (f32x4*)&s_vals[0];
        if (h == 1) s_red[nt * 64 + lane] = acc;
        __syncthreads();
        float* s_off = (float*)&s_vals[0] + 512;   // bytes 2048..3200
        if (h == 0) {
            const int oc = nt * 16 + lr;           // C: col=lr->oc, row=lg*4+r->px
            if (oc < NOFF) {
                const f32x4 o = s_red[nt * 64 + lane];
                const float bias = b_off[oc];
                #pragma unroll
                for (int r = 0; r < 4; ++r)
                    s_off[(lg * 4 + r) * NOFF + oc] = acc[r] + o[r] + bias;
            }
        }
    }
    __syncthreads();

    // ---- Phase 3: coords + bilinear weights + fast flag ----
    if (tid < NSAMP) {
        const float* s_off = (const float*)&s_vals[0] + 512;
        const int p  = tid / KKT;
        const int kk = tid - p * KKT;
        const int wo = wbase + p;
        const float py = (float)(ho - 1 + kk / 3) + s_off[p * NOFF + 2 * kk + 0];
        const float px = (float)(wo - 1 + kk % 3) + s_off[p * NOFF + 2 * kk + 1];
        const float fy = floorf(py), fx = floorf(px);
        const int y0 = (int)fy, x0 = (int)fx;
        const float dy = py - fy, dx = px - fx;
        s_yx[tid] = (y0 << 16) | (x0 & 0xffff);
        s_fast[tid] = (y0 >= ho - 2) & (y0 <= ho + 1) &
                      (x0 >= wbase - 4) & (x0 <= wbase + 18);
        s_bw[tid][0] = (1.f - dy) * (1.f - dx);
        s_bw[tid][1] = (1.f - dy) * dx;
        s_bw[tid][2] = dy * (1.f - dx);
        s_bw[tid][3] = dy * dx;
    }
    __syncthreads();

    // ---- Phase 4: bilinear, 8 channels/lane; f32x2 math (pk_fma), exact unpack ----
    for (int t = tid; t < NSAMP * 8; t += 256) {
        const int s  = t >> 3;
        const int c8 = (t & 7) << 3;
        const int p  = s / KKT;
        const int kk = s - p * KKT;
        const int yx = s_yx[s];
        const int y0 = yx >> 16;
        const int x0 = (int)(short)(yx & 0xffff);
        const f32x4 w = *(const f32x4*)&s_bw[s][0];
        bf16x8 o;
        if (s_fast[s]) {
            const int yr  = y0 - (ho - 2);
            const int xr  = x0 - (wbase - 4);
            const int e00 = ((yr * WCOLS + xr) << 6) + c8;
            const int sw0 = (xr & 7) << 3;
            const int sw1 = ((xr + 1) & 7) << 3;
            const u32x4 u00 = *(const u32x4*)&s_xw[e00 ^ sw0];
            const u32x4 u01 = *(const u32x4*)&s_xw[(e00 + 64) ^ sw1];
            const u32x4 u10 = *(const u32x4*)&s_xw[(e00 + WCOLS * 64) ^ sw0];
            const u32x4 u11 = *(const u32x4*)&s_xw[(e00 + (WCOLS + 1) * 64) ^ sw1];
            #pragma unroll
            for (int u = 0; u < 4; ++u) {
                f32x2 a = unpk(u00[u]) * w[0];
                a += unpk(u01[u]) * w[1];
                a += unpk(u10[u]) * w[2];
                a += unpk(u11[u]) * w[3];
                o[2 * u + 0] = (__bf16)a.x;
                o[2 * u + 1] = (__bf16)a.y;
            }
        } else {
            const int y1 = y0 + 1, x1 = x0 + 1;
            #pragma unroll
            for (int e = 0; e < 8; ++e) {
                const float* __restrict__ xc = xb + (size_t)(c8 + e) * (HH * WW);
                float v = 0.f;
                if (y0 >= 0 && y0 < HH) {
                    if (x0 >= 0 && x0 < WW) v += xc[y0 * WW + x0] * w[0];
                    if (x1 >= 0 && x1 < WW) v += xc[y0 * WW + x1] * w[1];
                }
                if (y1 >= 0 && y1 < HH) {
                    if (x0 >= 0 && x0 < WW) v += xc[y1 * WW + x0] * w[2];
                    if (x1 >= 0 && x1 < WW) v += xc[y1 * WW + x1] * w[3];
                }
                o[e] = (__bf16)v;
            }
        }
        const int ew = (kk * 64 + c8) ^ ((p & 7) << 3);
        *(bf16x8*)&s_vals[p * KTOT + ew] = o;
    }
    __syncthreads();

    // ---- Phase 5: 16x64x576 GEMM via MFMA bf16 ----
    f32x4 acc = {0.f, 0.f, 0.f, 0.f};
    const __bf16* __restrict__ bsrc = g_wb + (((size_t)wid * 4 + lg) * 16 + lr) * 8;
    #pragma unroll
    for (int kb = 0; kb < KB_N; ++kb) {
        const int ew = (kb * 32 + lg * 8) ^ ((lr & 7) << 3);
        const bf16x8 a  = *(const bf16x8*)&s_vals[lr * KTOT + ew];
        const bf16x8 bf = *(const bf16x8*)(bsrc + (size_t)kb * 2048);
        acc = __builtin_amdgcn_mfma_f32_16x16x32_bf16(a, bf, acc, 0, 0, 0);
    }
    const int cout = wid * 16 + lr;
    const size_t obase = (((size_t)b * COUT + cout) * HH + ho) * WW + wbase + lg * 4;
    *(f32x4*)&out[obase] = acc;
}

extern "C" void kernel_launch(void* const* d_in, const int* in_sizes, int n_in,
                              void* d_out, int out_size, void* d_ws, size_t ws_size,
                              hipStream_t stream) {
    const float* x     = (const float*)d_in[0];
    const float* w_off = (const float*)d_in[1];
    const float* b_off = (const float*)d_in[2];
    const float* w_dcn = (const float*)d_in[3];
    float* out = (float*)d_out;

    prep_w<<<216, 256, 0, stream>>>(w_dcn, w_off);

    const int nblocks = BATCH * HH * (WW / PIX);   // 8192
    deform_fused<<<nblocks, 256, 0, stream>>>(x, b_off, out);
}

// Round 9
// 91.826 us; speedup vs baseline: 48.1337x; 1.1073x over previous
//
#include <hip/hip_runtime.h>
#include <cmath>

#define BATCH 8
#define CIN   64
#define HH    128
#define WW    128
#define COUT  64
#define KKT   9            // K*K taps
#define NOFF  18           // 2*K*K offset channels
#define PIX   16           // pixels per block (one row segment)
#define KTOT  576          // GEMM K (tap-major: k = kk*64+ci)
#define KB_N  18           // K chunks of 32
#define WROWS 5            // window rows: ho-2 .. ho+2
#define WCOLS 24           // window cols: wbase-4 .. wbase+19
#define NSAMP (PIX*KKT)    // 144

typedef __bf16 bf16x8 __attribute__((ext_vector_type(8)));
typedef float  f32x4  __attribute__((ext_vector_type(4)));
typedef float  f32x2  __attribute__((ext_vector_type(2)));
typedef unsigned int u32;
typedef u32    u32x4  __attribute__((ext_vector_type(4)));

// Pre-packed bf16 weights in exact MFMA B-fragment order, tap-major K.
__device__ __bf16 g_wb[KB_N * 4 * 4 * 16 * 8];      // dcn:    [kb][wave4][lg][lr][e]
__device__ __bf16 g_wboff[KB_N * 2 * 4 * 16 * 8];   // offset: [kb][ntile2][lg][lr][e]

__global__ __launch_bounds__(256)
void prep_w(const float* __restrict__ w_dcn, const float* __restrict__ w_off) {
    const int idx = blockIdx.x * 256 + threadIdx.x;      // 55296 total
    if (idx < KB_N * 4 * 4 * 16 * 8) {
        const int e  = idx & 7;
        const int lr = (idx >> 3) & 15;
        const int lg = (idx >> 7) & 3;
        const int w  = (idx >> 9) & 3;
        const int kb = idx >> 11;
        const int cout = w * 16 + lr;
        const int k  = kb * 32 + lg * 8 + e;
        const int kk = k >> 6, ci = k & 63;
        g_wb[idx] = (__bf16)w_dcn[cout * KTOT + ci * KKT + kk];
    } else {
        const int j  = idx - KB_N * 4 * 4 * 16 * 8;
        const int e  = j & 7;
        const int lr = (j >> 3) & 15;
        const int lg = (j >> 7) & 3;
        const int nt = (j >> 9) & 1;
        const int kb = j >> 10;
        const int oc = nt * 16 + lr;
        const int k  = kb * 32 + lg * 8 + e;
        const int kk = k >> 6, ci = k & 63;
        g_wboff[j] = (oc < NOFF) ? (__bf16)w_off[oc * KTOT + ci * KKT + kk] : (__bf16)0.f;
    }
}

// exact bf16-pair -> f32x2 unpack (bit ops, no cvt)
static __device__ __forceinline__ f32x2 unpk(u32 v) {
    f32x2 r;
    r.x = __builtin_bit_cast(float, v << 16);
    r.y = __builtin_bit_cast(float, v & 0xffff0000u);
    return r;
}

__global__ __launch_bounds__(256)
void deform_fused(const float* __restrict__ x,
                  const float* __restrict__ b_off,
                  float* __restrict__ out) {
    // x window [yr][xr][ci] bf16, XOR-swizzled: elem ^= (xr&7)<<3
    __shared__ __align__(16) __bf16 s_xw[WROWS * WCOLS * 64];   // 15360 B
    // A operand [p][k], XOR-swizzled: col ^= (p&7)<<3. Aliased:
    // bytes [0,2048) = phase-2 reduce buf; bytes [2048,3200) = s_off.
    __shared__ __align__(16) __bf16 s_vals[PIX * KTOT];         // 18432 B
    __shared__ int   s_yx[NSAMP];        // (y0<<16)|(x0&0xffff)
    __shared__ float s_bw[NSAMP][4];     // bilinear corner weights
    __shared__ int   s_fast[NSAMP];

    const int blk   = blockIdx.x;
    const int wtile = blk % (WW / PIX);
    const int ho    = (blk / (WW / PIX)) % HH;
    const int b     = blk / ((WW / PIX) * HH);
    const int wbase = wtile * PIX;
    const int tid   = threadIdx.x;
    const int wid   = tid >> 6;
    const int lane  = tid & 63;
    const int lr    = lane & 15;
    const int lg    = lane >> 4;

    const float* __restrict__ xb = x + (size_t)b * CIN * HH * WW;
    const bool interior = (ho >= 2) & (ho <= HH - 3) & (wtile >= 1) & (wtile <= (WW / PIX) - 2);

    // ---- Phase 1: stage x window. Task map (c fast, ci mid, yr slow) so a wave's
    //      lanes span ci 0..10 -> slot and word bank bits both vary -> ~4-way max.
    for (int t = tid; t < 6 * 64 * WROWS; t += 256) {   // 1920 tasks
        const int c  = t % 6;
        const int ci = (t / 6) & 63;
        const int yr = t / 384;
        const int y  = ho - 2 + yr;
        const int xs = wbase - 4 + c * 4;
        float v0 = 0.f, v1 = 0.f, v2 = 0.f, v3 = 0.f;
        if (interior) {
            const float* __restrict__ rp = xb + (size_t)ci * (HH * WW) + y * WW + xs;
            const f32x4 v = *(const f32x4*)rp;   // 16B-aligned (wbase%16==0)
            v0 = v[0]; v1 = v[1]; v2 = v[2]; v3 = v[3];
        } else if (y >= 0 && y < HH) {
            const float* __restrict__ rp = xb + (size_t)ci * (HH * WW) + y * WW + xs;
            if (xs >= 0 && xs <= WW - 4) {
                const f32x4 v = *(const f32x4*)rp;
                v0 = v[0]; v1 = v[1]; v2 = v[2]; v3 = v[3];
            } else {
                if (xs + 0 >= 0 && xs + 0 < WW) v0 = rp[0];
                if (xs + 1 >= 0 && xs + 1 < WW) v1 = rp[1];
                if (xs + 2 >= 0 && xs + 2 < WW) v2 = rp[2];
                if (xs + 3 >= 0 && xs + 3 < WW) v3 = rp[3];
            }
        }
        const int eb = ((yr * WCOLS + c * 4) << 6) + ci;
        s_xw[(eb + 0 * 64) ^ (((c * 4 + 0) & 7) << 3)] = (__bf16)v0;
        s_xw[(eb + 1 * 64) ^ (((c * 4 + 1) & 7) << 3)] = (__bf16)v1;
        s_xw[(eb + 2 * 64) ^ (((c * 4 + 2) & 7) << 3)] = (__bf16)v2;
        s_xw[(eb + 3 * 64) ^ (((c * 4 + 3) & 7) << 3)] = (__bf16)v3;
    }
    __syncthreads();

    // ---- Phase 2: offset conv via MFMA bf16 (M=16, N=32[18 used], K=576 split 2) ----
    {
        const int nt = wid >> 1;
        const int h  = wid & 1;
        f32x4 acc = {0.f, 0.f, 0.f, 0.f};
        #pragma unroll
        for (int j = 0; j < 9; ++j) {
            const int kb    = h * 9 + j;
            const int kbase = kb * 32 + lg * 8;
            const int kk    = kbase >> 6;
            const int ci0   = kbase & 63;
            const int yr    = kk / 3 + 1;
            const int xr    = lr + kk % 3 + 3;
            const int elem  = (((yr * WCOLS + xr) << 6) + ci0) ^ ((xr & 7) << 3);
            const bf16x8 a  = *(const bf16x8*)&s_xw[elem];
            const bf16x8 bb = *(const bf16x8*)&g_wboff[(((kb * 2 + nt) * 4 + lg) * 16 + lr) * 8];
            acc = __builtin_amdgcn_mfma_f32_16x16x32_bf16(a, bb, acc, 0, 0, 0);
        }
        f32x4* s_red = (f32x4*)&s_vals[0];
        if (h == 1) s_red[nt * 64 + lane] = acc;
        __syncthreads();
        float* s_off = (float*)&s_vals[0] + 512;   // bytes 2048..3200
        if (h == 0) {
            const int oc = nt * 16 + lr;           // C: col=lr->oc, row=lg*4+r->px
            if (oc < NOFF) {
                const f32x4 o = s_red[nt * 64 + lane];
                const float bias = b_off[oc];
                #pragma unroll
                for (int r = 0; r < 4; ++r)
                    s_off[(lg * 4 + r) * NOFF + oc] = acc[r] + o[r] + bias;
            }
        }
    }
    __syncthreads();

    // ---- Phase 3: coords + bilinear weights + fast flag ----
    if (tid < NSAMP) {
        const float* s_off = (const float*)&s_vals[0] + 512;
        const int p  = tid / KKT;
        const int kk = tid - p * KKT;
        const int wo = wbase + p;
        const float py = (float)(ho - 1 + kk / 3) + s_off[p * NOFF + 2 * kk + 0];
        const float px = (float)(wo - 1 + kk % 3) + s_off[p * NOFF + 2 * kk + 1];
        const float fy = floorf(py), fx = floorf(px);
        const int y0 = (int)fy, x0 = (int)fx;
        const float dy = py - fy, dx = px - fx;
        s_yx[tid] = (y0 << 16) | (x0 & 0xffff);
        s_fast[tid] = (y0 >= ho - 2) & (y0 <= ho + 1) &
                      (x0 >= wbase - 4) & (x0 <= wbase + 18);
        s_bw[tid][0] = (1.f - dy) * (1.f - dx);
        s_bw[tid][1] = (1.f - dy) * dx;
        s_bw[tid][2] = dy * (1.f - dx);
        s_bw[tid][3] = dy * dx;
    }
    __syncthreads();

    // ---- Phase 4: bilinear, 8 channels/lane; f32x2 math (pk_fma), exact unpack ----
    for (int t = tid; t < NSAMP * 8; t += 256) {
        const int s  = t >> 3;
        const int c8 = (t & 7) << 3;
        const int p  = s / KKT;
        const int kk = s - p * KKT;
        const int yx = s_yx[s];
        const int y0 = yx >> 16;
        const int x0 = (int)(short)(yx & 0xffff);
        const f32x4 w = *(const f32x4*)&s_bw[s][0];
        bf16x8 o;
        if (s_fast[s]) {
            const int yr  = y0 - (ho - 2);
            const int xr  = x0 - (wbase - 4);
            const int e00 = ((yr * WCOLS + xr) << 6) + c8;
            const int sw0 = (xr & 7) << 3;
            const int sw1 = ((xr + 1) & 7) << 3;
            const u32x4 u00 = *(const u32x4*)&s_xw[e00 ^ sw0];
            const u32x4 u01 = *(const u32x4*)&s_xw[(e00 + 64) ^ sw1];
            const u32x4 u10 = *(const u32x4*)&s_xw[(e00 + WCOLS * 64) ^ sw0];
            const u32x4 u11 = *(const u32x4*)&s_xw[(e00 + (WCOLS + 1) * 64) ^ sw1];
            #pragma unroll
            for (int u = 0; u < 4; ++u) {
                f32x2 a = unpk(u00[u]) * w[0];
                a += unpk(u01[u]) * w[1];
                a += unpk(u10[u]) * w[2];
                a += unpk(u11[u]) * w[3];
                o[2 * u + 0] = (__bf16)a.x;
                o[2 * u + 1] = (__bf16)a.y;
            }
        } else {
            const int y1 = y0 + 1, x1 = x0 + 1;
            #pragma unroll
            for (int e = 0; e < 8; ++e) {
                const float* __restrict__ xc = xb + (size_t)(c8 + e) * (HH * WW);
                float v = 0.f;
                if (y0 >= 0 && y0 < HH) {
                    if (x0 >= 0 && x0 < WW) v += xc[y0 * WW + x0] * w[0];
                    if (x1 >= 0 && x1 < WW) v += xc[y0 * WW + x1] * w[1];
                }
                if (y1 >= 0 && y1 < HH) {
                    if (x0 >= 0 && x0 < WW) v += xc[y1 * WW + x0] * w[2];
                    if (x1 >= 0 && x1 < WW) v += xc[y1 * WW + x1] * w[3];
                }
                o[e] = (__bf16)v;
            }
        }
        const int ew = (kk * 64 + c8) ^ ((p & 7) << 3);
        *(bf16x8*)&s_vals[p * KTOT + ew] = o;
    }
    __syncthreads();

    // ---- Phase 5: 16x64x576 GEMM via MFMA bf16 ----
    f32x4 acc = {0.f, 0.f, 0.f, 0.f};
    const __bf16* __restrict__ bsrc = g_wb + (((size_t)wid * 4 + lg) * 16 + lr) * 8;
    #pragma unroll
    for (int kb = 0; kb < KB_N; ++kb) {
        const int ew = (kb * 32 + lg * 8) ^ ((lr & 7) << 3);
        const bf16x8 a  = *(const bf16x8*)&s_vals[lr * KTOT + ew];
        const bf16x8 bf = *(const bf16x8*)(bsrc + (size_t)kb * 2048);
        acc = __builtin_amdgcn_mfma_f32_16x16x32_bf16(a, bf, acc, 0, 0, 0);
    }
    const int cout = wid * 16 + lr;
    const size_t obase = (((size_t)b * COUT + cout) * HH + ho) * WW + wbase + lg * 4;
    *(f32x4*)&out[obase] = acc;
}

extern "C" void kernel_launch(void* const* d_in, const int* in_sizes, int n_in,
                              void* d_out, int out_size, void* d_ws, size_t ws_size,
                              hipStream_t stream) {
    const float* x     = (const float*)d_in[0];
    const float* w_off = (const float*)d_in[1];
    const float* b_off = (const float*)d_in[2];
    const float* w_dcn = (const float*)d_in[3];
    float* out = (float*)d_out;

    prep_w<<<216, 256, 0, stream>>>(w_dcn, w_off);

    const int nblocks = BATCH * HH * (WW / PIX);   // 8192
    deform_fused<<<nblocks, 256, 0, stream>>>(x, b_off, out);
}

// Round 10
// 81.436 us; speedup vs baseline: 54.2749x; 1.1276x over previous
//
#include <hip/hip_runtime.h>
#include <cmath>

#define BATCH 8
#define CIN   64
#define HH    128
#define WW    128
#define COUT  64
#define KKT   9            // K*K taps
#define NOFF  18           // 2*K*K offset channels
#define PIX   16           // pixels per block (one row segment)
#define KTOT  576          // GEMM K (tap-major: k = kk*64+ci)
#define WROWS 5            // window rows: ho-2 .. ho+2
#define WCOLS 24           // window cols: wbase-4 .. wbase+19
#define NSAMP (PIX*KKT)    // 144
#define KHA   256          // pass-A s_vals row length (taps 0..3, kb 0..7)
#define KHB   320          // pass-B s_vals row length (taps 4..8, kb 8..17)

typedef __bf16 bf16x8 __attribute__((ext_vector_type(8)));
typedef float  f32x4  __attribute__((ext_vector_type(4)));
typedef float  f32x2  __attribute__((ext_vector_type(2)));
typedef unsigned int u32;
typedef u32    u32x4  __attribute__((ext_vector_type(4)));

// Pre-packed bf16 weights in exact MFMA B-fragment order, tap-major K.
__device__ __bf16 g_wb[18 * 4 * 4 * 16 * 8];      // dcn:    [kb][wave4][lg][lr][e]
__device__ __bf16 g_wboff[18 * 2 * 4 * 16 * 8];   // offset: [kb][ntile2][lg][lr][e]

__global__ __launch_bounds__(256)
void prep_w(const float* __restrict__ w_dcn, const float* __restrict__ w_off) {
    const int idx = blockIdx.x * 256 + threadIdx.x;      // 55296 total
    if (idx < 18 * 4 * 4 * 16 * 8) {
        const int e  = idx & 7;
        const int lr = (idx >> 3) & 15;
        const int lg = (idx >> 7) & 3;
        const int w  = (idx >> 9) & 3;
        const int kb = idx >> 11;
        const int cout = w * 16 + lr;
        const int k  = kb * 32 + lg * 8 + e;
        const int kk = k >> 6, ci = k & 63;
        g_wb[idx] = (__bf16)w_dcn[cout * KTOT + ci * KKT + kk];
    } else {
        const int j  = idx - 18 * 4 * 4 * 16 * 8;
        const int e  = j & 7;
        const int lr = (j >> 3) & 15;
        const int lg = (j >> 7) & 3;
        const int nt = (j >> 9) & 1;
        const int kb = j >> 10;
        const int oc = nt * 16 + lr;
        const int k  = kb * 32 + lg * 8 + e;
        const int kk = k >> 6, ci = k & 63;
        g_wboff[j] = (oc < NOFF) ? (__bf16)w_off[oc * KTOT + ci * KKT + kk] : (__bf16)0.f;
    }
}

// exact bf16-pair -> f32x2 unpack (bit ops, no cvt)
static __device__ __forceinline__ f32x2 unpk(u32 v) {
    f32x2 r;
    r.x = __builtin_bit_cast(float, v << 16);
    r.y = __builtin_bit_cast(float, v & 0xffff0000u);
    return r;
}

__global__ __launch_bounds__(256)
void deform_fused(const float* __restrict__ x,
                  const float* __restrict__ b_off,
                  float* __restrict__ out) {
    // x window [yr][xr][ci] bf16, XOR-swizzled: elem ^= (xr&7)<<3
    __shared__ __align__(16) __bf16 s_xw[WROWS * WCOLS * 64];   // 15360 B
    // Half-K A operand [p][k'], XOR-swizzled: col ^= (p&7)<<3. Aliased:
    // bytes [0,2048) = phase-2 reduce buf; bytes [2048,3200) = s_off.
    __shared__ __align__(16) __bf16 s_vals[PIX * KHB];          // 10240 B
    __shared__ int   s_yx[NSAMP];        // (y0<<16)|(x0&0xffff)
    __shared__ float s_bw[NSAMP][4];     // bilinear corner weights
    __shared__ int   s_fast[NSAMP];

    const int blk   = blockIdx.x;
    const int wtile = blk % (WW / PIX);
    const int ho    = (blk / (WW / PIX)) % HH;
    const int b     = blk / ((WW / PIX) * HH);
    const int wbase = wtile * PIX;
    const int tid   = threadIdx.x;
    const int wid   = tid >> 6;
    const int lane  = tid & 63;
    const int lr    = lane & 15;
    const int lg    = lane >> 4;

    const float* __restrict__ xb = x + (size_t)b * CIN * HH * WW;
    const bool interior = (ho >= 2) & (ho <= HH - 3) & (wtile >= 1) & (wtile <= (WW / PIX) - 2);

    // ---- Phase 1: stage x window (c fast, ci mid, yr slow -> ~4-way max conflicts) ----
    for (int t = tid; t < 6 * 64 * WROWS; t += 256) {   // 1920 tasks
        const int c  = t % 6;
        const int ci = (t / 6) & 63;
        const int yr = t / 384;
        const int y  = ho - 2 + yr;
        const int xs = wbase - 4 + c * 4;
        float v0 = 0.f, v1 = 0.f, v2 = 0.f, v3 = 0.f;
        if (interior) {
            const float* __restrict__ rp = xb + (size_t)ci * (HH * WW) + y * WW + xs;
            const f32x4 v = *(const f32x4*)rp;   // 16B-aligned (wbase%16==0)
            v0 = v[0]; v1 = v[1]; v2 = v[2]; v3 = v[3];
        } else if (y >= 0 && y < HH) {
            const float* __restrict__ rp = xb + (size_t)ci * (HH * WW) + y * WW + xs;
            if (xs >= 0 && xs <= WW - 4) {
                const f32x4 v = *(const f32x4*)rp;
                v0 = v[0]; v1 = v[1]; v2 = v[2]; v3 = v[3];
            } else {
                if (xs + 0 >= 0 && xs + 0 < WW) v0 = rp[0];
                if (xs + 1 >= 0 && xs + 1 < WW) v1 = rp[1];
                if (xs + 2 >= 0 && xs + 2 < WW) v2 = rp[2];
                if (xs + 3 >= 0 && xs + 3 < WW) v3 = rp[3];
            }
        }
        const int eb = ((yr * WCOLS + c * 4) << 6) + ci;
        s_xw[(eb + 0 * 64) ^ (((c * 4 + 0) & 7) << 3)] = (__bf16)v0;
        s_xw[(eb + 1 * 64) ^ (((c * 4 + 1) & 7) << 3)] = (__bf16)v1;
        s_xw[(eb + 2 * 64) ^ (((c * 4 + 2) & 7) << 3)] = (__bf16)v2;
        s_xw[(eb + 3 * 64) ^ (((c * 4 + 3) & 7) << 3)] = (__bf16)v3;
    }
    __syncthreads();

    // ---- Phase 2: offset conv via MFMA bf16 (M=16, N=32[18 used], K=576 split 2) ----
    {
        const int nt = wid >> 1;
        const int h  = wid & 1;
        f32x4 acc = {0.f, 0.f, 0.f, 0.f};
        #pragma unroll
        for (int j = 0; j < 9; ++j) {
            const int kb    = h * 9 + j;
            const int kbase = kb * 32 + lg * 8;
            const int kk    = kbase >> 6;
            const int ci0   = kbase & 63;
            const int yr    = kk / 3 + 1;
            const int xr    = lr + kk % 3 + 3;
            const int elem  = (((yr * WCOLS + xr) << 6) + ci0) ^ ((xr & 7) << 3);
            const bf16x8 a  = *(const bf16x8*)&s_xw[elem];
            const bf16x8 bb = *(const bf16x8*)&g_wboff[(((kb * 2 + nt) * 4 + lg) * 16 + lr) * 8];
            acc = __builtin_amdgcn_mfma_f32_16x16x32_bf16(a, bb, acc, 0, 0, 0);
        }
        f32x4* s_red = (f32x4*)&s_vals[0];
        if (h == 1) s_red[nt * 64 + lane] = acc;
        __syncthreads();
        float* s_off = (float*)&s_vals[0] + 512;   // bytes 2048..3200
        if (h == 0) {
            const int oc = nt * 16 + lr;           // C: col=lr->oc, row=lg*4+r->px
            if (oc < NOFF) {
                const f32x4 o = s_red[nt * 64 + lane];
                const float bias = b_off[oc];
                #pragma unroll
                for (int r = 0; r < 4; ++r)
                    s_off[(lg * 4 + r) * NOFF + oc] = acc[r] + o[r] + bias;
            }
        }
    }
    __syncthreads();

    // ---- Phase 3: coords + bilinear weights + fast flag ----
    if (tid < NSAMP) {
        const float* s_off = (const float*)&s_vals[0] + 512;
        const int p  = tid / KKT;
        const int kk = tid - p * KKT;
        const int wo = wbase + p;
        const float py = (float)(ho - 1 + kk / 3) + s_off[p * NOFF + 2 * kk + 0];
        const float px = (float)(wo - 1 + kk % 3) + s_off[p * NOFF + 2 * kk + 1];
        const float fy = floorf(py), fx = floorf(px);
        const int y0 = (int)fy, x0 = (int)fx;
        const float dy = py - fy, dx = px - fx;
        s_yx[tid] = (y0 << 16) | (x0 & 0xffff);
        s_fast[tid] = (y0 >= ho - 2) & (y0 <= ho + 1) &
                      (x0 >= wbase - 4) & (x0 <= wbase + 18);
        s_bw[tid][0] = (1.f - dy) * (1.f - dx);
        s_bw[tid][1] = (1.f - dy) * dx;
        s_bw[tid][2] = dy * (1.f - dx);
        s_bw[tid][3] = dy * dx;
    }
    __syncthreads();

    // ---- Bilinear task body (identical math to round 9) ----
    auto run_task = [&](int m, int p, int kkl, int c8, int KH) {
        const int yx = s_yx[m];
        const int y0 = yx >> 16;
        const int x0 = (int)(short)(yx & 0xffff);
        const f32x4 w = *(const f32x4*)&s_bw[m][0];
        bf16x8 o;
        if (s_fast[m]) {
            const int yr  = y0 - (ho - 2);
            const int xr  = x0 - (wbase - 4);
            const int e00 = ((yr * WCOLS + xr) << 6) + c8;
            const int sw0 = (xr & 7) << 3;
            const int sw1 = ((xr + 1) & 7) << 3;
            const u32x4 u00 = *(const u32x4*)&s_xw[e00 ^ sw0];
            const u32x4 u01 = *(const u32x4*)&s_xw[(e00 + 64) ^ sw1];
            const u32x4 u10 = *(const u32x4*)&s_xw[(e00 + WCOLS * 64) ^ sw0];
            const u32x4 u11 = *(const u32x4*)&s_xw[(e00 + (WCOLS + 1) * 64) ^ sw1];
            #pragma unroll
            for (int u = 0; u < 4; ++u) {
                f32x2 a = unpk(u00[u]) * w[0];
                a += unpk(u01[u]) * w[1];
                a += unpk(u10[u]) * w[2];
                a += unpk(u11[u]) * w[3];
                o[2 * u + 0] = (__bf16)a.x;
                o[2 * u + 1] = (__bf16)a.y;
            }
        } else {
            const int y1 = y0 + 1, x1 = x0 + 1;
            #pragma unroll
            for (int e = 0; e < 8; ++e) {
                const float* __restrict__ xc = xb + (size_t)(c8 + e) * (HH * WW);
                float v = 0.f;
                if (y0 >= 0 && y0 < HH) {
                    if (x0 >= 0 && x0 < WW) v += xc[y0 * WW + x0] * w[0];
                    if (x1 >= 0 && x1 < WW) v += xc[y0 * WW + x1] * w[1];
                }
                if (y1 >= 0 && y1 < HH) {
                    if (x0 >= 0 && x0 < WW) v += xc[y1 * WW + x0] * w[2];
                    if (x1 >= 0 && x1 < WW) v += xc[y1 * WW + x1] * w[3];
                }
                o[e] = (__bf16)v;
            }
        }
        const int ew = (kkl * 64 + c8) ^ ((p & 7) << 3);
        *(bf16x8*)&s_vals[p * KH + ew] = o;
    };

    f32x4 acc = {0.f, 0.f, 0.f, 0.f};
    const __bf16* __restrict__ bsrc = g_wb + (((size_t)wid * 4 + lg) * 16 + lr) * 8;

    // ---- Phase 4a: bilinear for taps 0..3 (64 samples x 8 octets = 512 tasks) ----
    for (int t = tid; t < 512; t += 256) {
        const int s4 = t >> 3, c8 = (t & 7) << 3;
        const int p = s4 >> 2, kkl = s4 & 3;
        run_task(p * KKT + kkl, p, kkl, c8, KHA);
    }
    __syncthreads();

    // ---- Phase 5a: GEMM kb 0..7 ----
    #pragma unroll
    for (int kb = 0; kb < 8; ++kb) {
        const int ew = (kb * 32 + lg * 8) ^ ((lr & 7) << 3);
        const bf16x8 a  = *(const bf16x8*)&s_vals[lr * KHA + ew];
        const bf16x8 bf = *(const bf16x8*)(bsrc + (size_t)kb * 2048);
        acc = __builtin_amdgcn_mfma_f32_16x16x32_bf16(a, bf, acc, 0, 0, 0);
    }
    __syncthreads();

    // ---- Phase 4b: bilinear for taps 4..8 (80 samples x 8 octets = 640 tasks) ----
    for (int t = tid; t < 640; t += 256) {
        const int s5 = t >> 3, c8 = (t & 7) << 3;
        const int p = s5 / 5, kkl = s5 - p * 5;
        run_task(p * KKT + 4 + kkl, p, kkl, c8, KHB);
    }
    __syncthreads();

    // ---- Phase 5b: GEMM kb 8..17 ----
    #pragma unroll
    for (int kb = 8; kb < 18; ++kb) {
        const int ew = ((kb - 8) * 32 + lg * 8) ^ ((lr & 7) << 3);
        const bf16x8 a  = *(const bf16x8*)&s_vals[lr * KHB + ew];
        const bf16x8 bf = *(const bf16x8*)(bsrc + (size_t)kb * 2048);
        acc = __builtin_amdgcn_mfma_f32_16x16x32_bf16(a, bf, acc, 0, 0, 0);
    }

    const int cout = wid * 16 + lr;
    const size_t obase = (((size_t)b * COUT + cout) * HH + ho) * WW + wbase + lg * 4;
    *(f32x4*)&out[obase] = acc;
}

extern "C" void kernel_launch(void* const* d_in, const int* in_sizes, int n_in,
                              void* d_out, int out_size, void* d_ws, size_t ws_size,
                              hipStream_t stream) {
    const float* x     = (const float*)d_in[0];
    const float* w_off = (const float*)d_in[1];
    const float* b_off = (const float*)d_in[2];
    const float* w_dcn = (const float*)d_in[3];
    float* out = (float*)d_out;

    prep_w<<<216, 256, 0, stream>>>(w_dcn, w_off);

    const int nblocks = BATCH * HH * (WW / PIX);   // 8192
    deform_fused<<<nblocks, 256, 0, stream>>>(x, b_off, out);
}

// Round 11
// 81.279 us; speedup vs baseline: 54.3799x; 1.0019x over previous
//
#include <hip/hip_runtime.h>
#include <cmath>

#define BATCH 8
#define CIN   64
#define HH    128
#define WW    128
#define COUT  64
#define KKT   9            // K*K taps
#define NOFF  18           // 2*K*K offset channels
#define PIX   16           // pixels per block (one row segment)
#define KTOT  576          // GEMM K (tap-major: k = kk*64+ci)
#define WROWS 5            // window rows: ho-2 .. ho+2
#define WCOLS 24           // window cols: wbase-4 .. wbase+19
#define NSAMP (PIX*KKT)    // 144
#define KH3   192          // per-pass s_vals row length (3 taps x 64 ci)

typedef __bf16 bf16x8 __attribute__((ext_vector_type(8)));
typedef float  f32x4  __attribute__((ext_vector_type(4)));
typedef float  f32x2  __attribute__((ext_vector_type(2)));
typedef unsigned int u32;
typedef u32    u32x4  __attribute__((ext_vector_type(4)));

// Pre-packed bf16 weights in exact MFMA B-fragment order, tap-major K.
__device__ __bf16 g_wb[18 * 4 * 4 * 16 * 8];      // dcn:    [kb][wave4][lg][lr][e]
__device__ __bf16 g_wboff[18 * 2 * 4 * 16 * 8];   // offset: [kb][ntile2][lg][lr][e]

__global__ __launch_bounds__(256)
void prep_w(const float* __restrict__ w_dcn, const float* __restrict__ w_off) {
    const int idx = blockIdx.x * 256 + threadIdx.x;      // 55296 total
    if (idx < 18 * 4 * 4 * 16 * 8) {
        const int e  = idx & 7;
        const int lr = (idx >> 3) & 15;
        const int lg = (idx >> 7) & 3;
        const int w  = (idx >> 9) & 3;
        const int kb = idx >> 11;
        const int cout = w * 16 + lr;
        const int k  = kb * 32 + lg * 8 + e;
        const int kk = k >> 6, ci = k & 63;
        g_wb[idx] = (__bf16)w_dcn[cout * KTOT + ci * KKT + kk];
    } else {
        const int j  = idx - 18 * 4 * 4 * 16 * 8;
        const int e  = j & 7;
        const int lr = (j >> 3) & 15;
        const int lg = (j >> 7) & 3;
        const int nt = (j >> 9) & 1;
        const int kb = j >> 10;
        const int oc = nt * 16 + lr;
        const int k  = kb * 32 + lg * 8 + e;
        const int kk = k >> 6, ci = k & 63;
        g_wboff[j] = (oc < NOFF) ? (__bf16)w_off[oc * KTOT + ci * KKT + kk] : (__bf16)0.f;
    }
}

// exact bf16-pair -> f32x2 unpack (bit ops, no cvt)
static __device__ __forceinline__ f32x2 unpk(u32 v) {
    f32x2 r;
    r.x = __builtin_bit_cast(float, v << 16);
    r.y = __builtin_bit_cast(float, v & 0xffff0000u);
    return r;
}

__global__ __launch_bounds__(256)
void deform_fused(const float* __restrict__ x,
                  const float* __restrict__ b_off,
                  float* __restrict__ out) {
    // x window [yr][xr][ci] bf16, XOR-swizzled: elem ^= (xr&7)<<3
    __shared__ __align__(16) __bf16 s_xw[WROWS * WCOLS * 64];   // 15360 B
    // Third-K A operand [p][k'], XOR-swizzled: col ^= (p&7)<<3. Aliased:
    // bytes [0,2048) = phase-2 reduce buf; bytes [2048,3200) = s_off.
    __shared__ __align__(16) __bf16 s_vals[PIX * KH3];          // 6144 B
    __shared__ int   s_yx[NSAMP];        // (y0<<16)|(x0&0xffff)
    __shared__ float s_bw[NSAMP][4];     // bilinear corner weights
    __shared__ int   s_fast[NSAMP];

    const int blk   = blockIdx.x;
    const int wtile = blk % (WW / PIX);
    const int ho    = (blk / (WW / PIX)) % HH;
    const int b     = blk / ((WW / PIX) * HH);
    const int wbase = wtile * PIX;
    const int tid   = threadIdx.x;
    const int wid   = tid >> 6;
    const int lane  = tid & 63;
    const int lr    = lane & 15;
    const int lg    = lane >> 4;

    const float* __restrict__ xb = x + (size_t)b * CIN * HH * WW;
    const bool interior = (ho >= 2) & (ho <= HH - 3) & (wtile >= 1) & (wtile <= (WW / PIX) - 2);

    // ---- Phase 1: stage x window (c fast, ci mid, yr slow -> ~4-way max conflicts) ----
    for (int t = tid; t < 6 * 64 * WROWS; t += 256) {   // 1920 tasks
        const int c  = t % 6;
        const int ci = (t / 6) & 63;
        const int yr = t / 384;
        const int y  = ho - 2 + yr;
        const int xs = wbase - 4 + c * 4;
        float v0 = 0.f, v1 = 0.f, v2 = 0.f, v3 = 0.f;
        if (interior) {
            const float* __restrict__ rp = xb + (size_t)ci * (HH * WW) + y * WW + xs;
            const f32x4 v = *(const f32x4*)rp;   // 16B-aligned (wbase%16==0)
            v0 = v[0]; v1 = v[1]; v2 = v[2]; v3 = v[3];
        } else if (y >= 0 && y < HH) {
            const float* __restrict__ rp = xb + (size_t)ci * (HH * WW) + y * WW + xs;
            if (xs >= 0 && xs <= WW - 4) {
                const f32x4 v = *(const f32x4*)rp;
                v0 = v[0]; v1 = v[1]; v2 = v[2]; v3 = v[3];
            } else {
                if (xs + 0 >= 0 && xs + 0 < WW) v0 = rp[0];
                if (xs + 1 >= 0 && xs + 1 < WW) v1 = rp[1];
                if (xs + 2 >= 0 && xs + 2 < WW) v2 = rp[2];
                if (xs + 3 >= 0 && xs + 3 < WW) v3 = rp[3];
            }
        }
        const int eb = ((yr * WCOLS + c * 4) << 6) + ci;
        s_xw[(eb + 0 * 64) ^ (((c * 4 + 0) & 7) << 3)] = (__bf16)v0;
        s_xw[(eb + 1 * 64) ^ (((c * 4 + 1) & 7) << 3)] = (__bf16)v1;
        s_xw[(eb + 2 * 64) ^ (((c * 4 + 2) & 7) << 3)] = (__bf16)v2;
        s_xw[(eb + 3 * 64) ^ (((c * 4 + 3) & 7) << 3)] = (__bf16)v3;
    }
    __syncthreads();

    // ---- Phase 2: offset conv via MFMA bf16 (M=16, N=32[18 used], K=576 split 2) ----
    {
        const int nt = wid >> 1;
        const int h  = wid & 1;
        f32x4 acc = {0.f, 0.f, 0.f, 0.f};
        #pragma unroll
        for (int j = 0; j < 9; ++j) {
            const int kb    = h * 9 + j;
            const int kbase = kb * 32 + lg * 8;
            const int kk    = kbase >> 6;
            const int ci0   = kbase & 63;
            const int yr    = kk / 3 + 1;
            const int xr    = lr + kk % 3 + 3;
            const int elem  = (((yr * WCOLS + xr) << 6) + ci0) ^ ((xr & 7) << 3);
            const bf16x8 a  = *(const bf16x8*)&s_xw[elem];
            const bf16x8 bb = *(const bf16x8*)&g_wboff[(((kb * 2 + nt) * 4 + lg) * 16 + lr) * 8];
            acc = __builtin_amdgcn_mfma_f32_16x16x32_bf16(a, bb, acc, 0, 0, 0);
        }
        f32x4* s_red = (f32x4*)&s_vals[0];
        if (h == 1) s_red[nt * 64 + lane] = acc;
        __syncthreads();
        float* s_off = (float*)&s_vals[0] + 512;   // bytes 2048..3200
        if (h == 0) {
            const int oc = nt * 16 + lr;           // C: col=lr->oc, row=lg*4+r->px
            if (oc < NOFF) {
                const f32x4 o = s_red[nt * 64 + lane];
                const float bias = b_off[oc];
                #pragma unroll
                for (int r = 0; r < 4; ++r)
                    s_off[(lg * 4 + r) * NOFF + oc] = acc[r] + o[r] + bias;
            }
        }
    }
    __syncthreads();

    // ---- Phase 3: coords + bilinear weights + fast flag ----
    if (tid < NSAMP) {
        const float* s_off = (const float*)&s_vals[0] + 512;
        const int p  = tid / KKT;
        const int kk = tid - p * KKT;
        const int wo = wbase + p;
        const float py = (float)(ho - 1 + kk / 3) + s_off[p * NOFF + 2 * kk + 0];
        const float px = (float)(wo - 1 + kk % 3) + s_off[p * NOFF + 2 * kk + 1];
        const float fy = floorf(py), fx = floorf(px);
        const int y0 = (int)fy, x0 = (int)fx;
        const float dy = py - fy, dx = px - fx;
        s_yx[tid] = (y0 << 16) | (x0 & 0xffff);
        s_fast[tid] = (y0 >= ho - 2) & (y0 <= ho + 1) &
                      (x0 >= wbase - 4) & (x0 <= wbase + 18);
        s_bw[tid][0] = (1.f - dy) * (1.f - dx);
        s_bw[tid][1] = (1.f - dy) * dx;
        s_bw[tid][2] = dy * (1.f - dx);
        s_bw[tid][3] = dy * dx;
    }
    __syncthreads();

    // ---- Bilinear task body (identical math to round 10) ----
    auto run_task = [&](int m, int p, int kkl, int c8) {
        const int yx = s_yx[m];
        const int y0 = yx >> 16;
        const int x0 = (int)(short)(yx & 0xffff);
        const f32x4 w = *(const f32x4*)&s_bw[m][0];
        bf16x8 o;
        if (s_fast[m]) {
            const int yr  = y0 - (ho - 2);
            const int xr  = x0 - (wbase - 4);
            const int e00 = ((yr * WCOLS + xr) << 6) + c8;
            const int sw0 = (xr & 7) << 3;
            const int sw1 = ((xr + 1) & 7) << 3;
            const u32x4 u00 = *(const u32x4*)&s_xw[e00 ^ sw0];
            const u32x4 u01 = *(const u32x4*)&s_xw[(e00 + 64) ^ sw1];
            const u32x4 u10 = *(const u32x4*)&s_xw[(e00 + WCOLS * 64) ^ sw0];
            const u32x4 u11 = *(const u32x4*)&s_xw[(e00 + (WCOLS + 1) * 64) ^ sw1];
            #pragma unroll
            for (int u = 0; u < 4; ++u) {
                f32x2 a = unpk(u00[u]) * w[0];
                a += unpk(u01[u]) * w[1];
                a += unpk(u10[u]) * w[2];
                a += unpk(u11[u]) * w[3];
                o[2 * u + 0] = (__bf16)a.x;
                o[2 * u + 1] = (__bf16)a.y;
            }
        } else {
            const int y1 = y0 + 1, x1 = x0 + 1;
            #pragma unroll
            for (int e = 0; e < 8; ++e) {
                const float* __restrict__ xc = xb + (size_t)(c8 + e) * (HH * WW);
                float v = 0.f;
                if (y0 >= 0 && y0 < HH) {
                    if (x0 >= 0 && x0 < WW) v += xc[y0 * WW + x0] * w[0];
                    if (x1 >= 0 && x1 < WW) v += xc[y0 * WW + x1] * w[1];
                }
                if (y1 >= 0 && y1 < HH) {
                    if (x0 >= 0 && x0 < WW) v += xc[y1 * WW + x0] * w[2];
                    if (x1 >= 0 && x1 < WW) v += xc[y1 * WW + x1] * w[3];
                }
                o[e] = (__bf16)v;
            }
        }
        const int ew = (kkl * 64 + c8) ^ ((p & 7) << 3);
        *(bf16x8*)&s_vals[p * KH3 + ew] = o;
    };

    f32x4 acc = {0.f, 0.f, 0.f, 0.f};
    const __bf16* __restrict__ bsrc = g_wb + (((size_t)wid * 4 + lg) * 16 + lr) * 8;

    // ---- Three K-passes: taps {0..2}, {3..5}, {6..8}; 6 MFMA kb each ----
    #pragma unroll 1
    for (int pass = 0; pass < 3; ++pass) {
        // bilinear: 48 samples x 8 octets = 384 tasks
        for (int t = tid; t < 384; t += 256) {
            const int s3 = t >> 3, c8 = (t & 7) << 3;
            const int p = s3 / 3, kkl = s3 - p * 3;
            run_task(p * KKT + pass * 3 + kkl, p, kkl, c8);
        }
        __syncthreads();
        // GEMM: kb = pass*6 .. pass*6+5
        #pragma unroll
        for (int j = 0; j < 6; ++j) {
            const int kb = pass * 6 + j;
            const int ew = (j * 32 + lg * 8) ^ ((lr & 7) << 3);
            const bf16x8 a  = *(const bf16x8*)&s_vals[lr * KH3 + ew];
            const bf16x8 bf = *(const bf16x8*)(bsrc + (size_t)kb * 2048);
            acc = __builtin_amdgcn_mfma_f32_16x16x32_bf16(a, bf, acc, 0, 0, 0);
        }
        if (pass < 2) __syncthreads();
    }

    const int cout = wid * 16 + lr;
    const size_t obase = (((size_t)b * COUT + cout) * HH + ho) * WW + wbase + lg * 4;
    *(f32x4*)&out[obase] = acc;
}

extern "C" void kernel_launch(void* const* d_in, const int* in_sizes, int n_in,
                              void* d_out, int out_size, void* d_ws, size_t ws_size,
                              hipStream_t stream) {
    const float* x     = (const float*)d_in[0];
    const float* w_off = (const float*)d_in[1];
    const float* b_off = (const float*)d_in[2];
    const float* w_dcn = (const float*)d_in[3];
    float* out = (float*)d_out;

    prep_w<<<216, 256, 0, stream>>>(w_dcn, w_off);

    const int nblocks = BATCH * HH * (WW / PIX);   // 8192
    deform_fused<<<nblocks, 256, 0, stream>>>(x, b_off, out);
}

// Round 12
// 70.002 us; speedup vs baseline: 63.1401x; 1.1611x over previous
//
#include <hip/hip_runtime.h>
#include <cmath>

#define BATCH 8
#define CIN   64
#define HH    128
#define WW    128
#define COUT  64
#define KKT   9            // K*K taps
#define NOFF  18           // 2*K*K offset channels
#define PIX   16           // pixels per row segment
#define NPX   32           // output pixels per block (2 rows x 16)
#define KTOT  576          // GEMM K (tap-major: k = kk*64+ci)
#define WROWS 6            // window rows: r0-2 .. r0+3
#define WCOLS 24           // window cols: wbase-4 .. wbase+19
#define NSAMP (NPX*KKT)    // 288
#define KH3   192          // per-pass s_vals row length (3 taps x 64 ci)

typedef __bf16 bf16x8 __attribute__((ext_vector_type(8)));
typedef float  f32x4  __attribute__((ext_vector_type(4)));
typedef float  f32x2  __attribute__((ext_vector_type(2)));
typedef unsigned int u32;
typedef u32    u32x4  __attribute__((ext_vector_type(4)));

// Pre-packed bf16 weights in exact MFMA B-fragment order, tap-major K.
__device__ __bf16 g_wb[18 * 4 * 4 * 16 * 8];      // dcn:    [kb][wave4][lg][lr][e]
__device__ __bf16 g_wboff[18 * 2 * 4 * 16 * 8];   // offset: [kb][ntile2][lg][lr][e]

__global__ __launch_bounds__(256)
void prep_w(const float* __restrict__ w_dcn, const float* __restrict__ w_off) {
    const int idx = blockIdx.x * 256 + threadIdx.x;      // 55296 total
    if (idx < 18 * 4 * 4 * 16 * 8) {
        const int e  = idx & 7;
        const int lr = (idx >> 3) & 15;
        const int lg = (idx >> 7) & 3;
        const int w  = (idx >> 9) & 3;
        const int kb = idx >> 11;
        const int cout = w * 16 + lr;
        const int k  = kb * 32 + lg * 8 + e;
        const int kk = k >> 6, ci = k & 63;
        g_wb[idx] = (__bf16)w_dcn[cout * KTOT + ci * KKT + kk];
    } else {
        const int j  = idx - 18 * 4 * 4 * 16 * 8;
        const int e  = j & 7;
        const int lr = (j >> 3) & 15;
        const int lg = (j >> 7) & 3;
        const int nt = (j >> 9) & 1;
        const int kb = j >> 10;
        const int oc = nt * 16 + lr;
        const int k  = kb * 32 + lg * 8 + e;
        const int kk = k >> 6, ci = k & 63;
        g_wboff[j] = (oc < NOFF) ? (__bf16)w_off[oc * KTOT + ci * KKT + kk] : (__bf16)0.f;
    }
}

// exact bf16-pair -> f32x2 unpack (bit ops, no cvt)
static __device__ __forceinline__ f32x2 unpk(u32 v) {
    f32x2 r;
    r.x = __builtin_bit_cast(float, v << 16);
    r.y = __builtin_bit_cast(float, v & 0xffff0000u);
    return r;
}

__global__ __launch_bounds__(256)
void deform_fused(const float* __restrict__ x,
                  const float* __restrict__ b_off,
                  float* __restrict__ out) {
    // x window [yr][xr][ci] bf16, XOR-swizzled: elem ^= (xr&7)<<3
    __shared__ __align__(16) __bf16 s_xw[WROWS * WCOLS * 64];   // 18432 B
    // Third-K A operand [p][k'], XOR-swizzled: col ^= (p&7)<<3
    __shared__ __align__(16) __bf16 s_vals[NPX * KH3];          // 12288 B
    __shared__ float s_off[NPX * NOFF];                         // 2304 B
    __shared__ int   s_yx[NSAMP];        // (y0<<16)|(x0&0xffff)
    __shared__ float s_bw[NSAMP][4];     // bilinear corner weights
    __shared__ int   s_fast[NSAMP];

    const int blk   = blockIdx.x;                  // 4096 blocks
    const int wtile = blk % (WW / PIX);
    const int r0    = ((blk / (WW / PIX)) % (HH / 2)) * 2;
    const int b     = blk / ((WW / PIX) * (HH / 2));
    const int wbase = wtile * PIX;
    const int tid   = threadIdx.x;
    const int wid   = tid >> 6;
    const int lane  = tid & 63;
    const int lr    = lane & 15;
    const int lg    = lane >> 4;

    const float* __restrict__ xb = x + (size_t)b * CIN * HH * WW;
    const bool interior = (r0 >= 2) & (r0 <= HH - 4) & (wtile >= 1) & (wtile <= (WW / PIX) - 2);

    // ---- Phase 1: stage 6-row x window (c fast, ci mid, yr slow) ----
    for (int t = tid; t < 6 * 64 * WROWS; t += 256) {   // 2304 tasks
        const int c  = t % 6;
        const int ci = (t / 6) & 63;
        const int yr = t / 384;                          // 0..5
        const int y  = r0 - 2 + yr;
        const int xs = wbase - 4 + c * 4;
        float v0 = 0.f, v1 = 0.f, v2 = 0.f, v3 = 0.f;
        if (interior) {
            const float* __restrict__ rp = xb + (size_t)ci * (HH * WW) + y * WW + xs;
            const f32x4 v = *(const f32x4*)rp;   // 16B-aligned (wbase%16==0)
            v0 = v[0]; v1 = v[1]; v2 = v[2]; v3 = v[3];
        } else if (y >= 0 && y < HH) {
            const float* __restrict__ rp = xb + (size_t)ci * (HH * WW) + y * WW + xs;
            if (xs >= 0 && xs <= WW - 4) {
                const f32x4 v = *(const f32x4*)rp;
                v0 = v[0]; v1 = v[1]; v2 = v[2]; v3 = v[3];
            } else {
                if (xs + 0 >= 0 && xs + 0 < WW) v0 = rp[0];
                if (xs + 1 >= 0 && xs + 1 < WW) v1 = rp[1];
                if (xs + 2 >= 0 && xs + 2 < WW) v2 = rp[2];
                if (xs + 3 >= 0 && xs + 3 < WW) v3 = rp[3];
            }
        }
        const int eb = ((yr * WCOLS + c * 4) << 6) + ci;
        s_xw[(eb + 0 * 64) ^ (((c * 4 + 0) & 7) << 3)] = (__bf16)v0;
        s_xw[(eb + 1 * 64) ^ (((c * 4 + 1) & 7) << 3)] = (__bf16)v1;
        s_xw[(eb + 2 * 64) ^ (((c * 4 + 2) & 7) << 3)] = (__bf16)v2;
        s_xw[(eb + 3 * 64) ^ (((c * 4 + 3) & 7) << 3)] = (__bf16)v3;
    }
    __syncthreads();

    // ---- Phase 2: offset conv via MFMA (M=16 px-group, N=32[18 used], full K per wave)
    //      wave wid -> (pg = wid>>1 pixel-row-group, nt = wid&1 oc-tile); no K-split reduce.
    {
        const int pg = wid >> 1;
        const int nt = wid & 1;
        f32x4 acc = {0.f, 0.f, 0.f, 0.f};
        #pragma unroll
        for (int kb = 0; kb < 18; ++kb) {
            const int kbase = kb * 32 + lg * 8;
            const int kk    = kbase >> 6;
            const int ci0   = kbase & 63;
            const int yr    = pg + kk / 3 + 1;           // window row for y = r0+pg+ky-1
            const int xr    = lr + kk % 3 + 3;
            const int elem  = (((yr * WCOLS + xr) << 6) + ci0) ^ ((xr & 7) << 3);
            const bf16x8 a  = *(const bf16x8*)&s_xw[elem];
            const bf16x8 bb = *(const bf16x8*)&g_wboff[(((kb * 2 + nt) * 4 + lg) * 16 + lr) * 8];
            acc = __builtin_amdgcn_mfma_f32_16x16x32_bf16(a, bb, acc, 0, 0, 0);
        }
        const int oc = nt * 16 + lr;                     // C: col=lr->oc, row=lg*4+r->px-in-group
        if (oc < NOFF) {
            const float bias = b_off[oc];
            #pragma unroll
            for (int r = 0; r < 4; ++r)
                s_off[(pg * 16 + lg * 4 + r) * NOFF + oc] = acc[r] + bias;
        }
    }
    __syncthreads();

    // ---- Phase 3: coords + bilinear weights + fast flag (288 samples) ----
    for (int m = tid; m < NSAMP; m += 256) {
        const int p  = m / KKT;                          // 0..31
        const int kk = m - p * KKT;
        const int hp = r0 + (p >> 4);                    // output row
        const int wo = wbase + (p & 15);
        const float py = (float)(hp - 1 + kk / 3) + s_off[p * NOFF + 2 * kk + 0];
        const float px = (float)(wo - 1 + kk % 3) + s_off[p * NOFF + 2 * kk + 1];
        const float fy = floorf(py), fx = floorf(px);
        const int y0 = (int)fy, x0 = (int)fx;
        const float dy = py - fy, dx = px - fx;
        s_yx[m] = (y0 << 16) | (x0 & 0xffff);
        s_fast[m] = (y0 >= r0 - 2) & (y0 <= r0 + 2) &
                    (x0 >= wbase - 4) & (x0 <= wbase + 18);
        s_bw[m][0] = (1.f - dy) * (1.f - dx);
        s_bw[m][1] = (1.f - dy) * dx;
        s_bw[m][2] = dy * (1.f - dx);
        s_bw[m][3] = dy * dx;
    }
    __syncthreads();

    // ---- Bilinear task body (identical math to round 11) ----
    auto run_task = [&](int m, int p, int kkl, int c8) {
        const int yx = s_yx[m];
        const int y0 = yx >> 16;
        const int x0 = (int)(short)(yx & 0xffff);
        const f32x4 w = *(const f32x4*)&s_bw[m][0];
        bf16x8 o;
        if (s_fast[m]) {
            const int yr  = y0 - (r0 - 2);
            const int xr  = x0 - (wbase - 4);
            const int e00 = ((yr * WCOLS + xr) << 6) + c8;
            const int sw0 = (xr & 7) << 3;
            const int sw1 = ((xr + 1) & 7) << 3;
            const u32x4 u00 = *(const u32x4*)&s_xw[e00 ^ sw0];
            const u32x4 u01 = *(const u32x4*)&s_xw[(e00 + 64) ^ sw1];
            const u32x4 u10 = *(const u32x4*)&s_xw[(e00 + WCOLS * 64) ^ sw0];
            const u32x4 u11 = *(const u32x4*)&s_xw[(e00 + (WCOLS + 1) * 64) ^ sw1];
            #pragma unroll
            for (int u = 0; u < 4; ++u) {
                f32x2 a = unpk(u00[u]) * w[0];
                a += unpk(u01[u]) * w[1];
                a += unpk(u10[u]) * w[2];
                a += unpk(u11[u]) * w[3];
                o[2 * u + 0] = (__bf16)a.x;
                o[2 * u + 1] = (__bf16)a.y;
            }
        } else {
            const int y1 = y0 + 1, x1 = x0 + 1;
            #pragma unroll
            for (int e = 0; e < 8; ++e) {
                const float* __restrict__ xc = xb + (size_t)(c8 + e) * (HH * WW);
                float v = 0.f;
                if (y0 >= 0 && y0 < HH) {
                    if (x0 >= 0 && x0 < WW) v += xc[y0 * WW + x0] * w[0];
                    if (x1 >= 0 && x1 < WW) v += xc[y0 * WW + x1] * w[1];
                }
                if (y1 >= 0 && y1 < HH) {
                    if (x0 >= 0 && x0 < WW) v += xc[y1 * WW + x0] * w[2];
                    if (x1 >= 0 && x1 < WW) v += xc[y1 * WW + x1] * w[3];
                }
                o[e] = (__bf16)v;
            }
        }
        const int ew = (kkl * 64 + c8) ^ ((p & 7) << 3);
        *(bf16x8*)&s_vals[p * KH3 + ew] = o;
    };

    f32x4 acc0 = {0.f, 0.f, 0.f, 0.f};
    f32x4 acc1 = {0.f, 0.f, 0.f, 0.f};
    const __bf16* __restrict__ bsrc = g_wb + (((size_t)wid * 4 + lg) * 16 + lr) * 8;

    // ---- Three K-passes: taps {0..2}, {3..5}, {6..8}; 6 kb x 2 px-groups each ----
    #pragma unroll 1
    for (int pass = 0; pass < 3; ++pass) {
        // bilinear: 32 px x 3 taps x 8 octets = 768 tasks
        for (int t = tid; t < 768; t += 256) {
            const int s3 = t >> 3, c8 = (t & 7) << 3;
            const int p = s3 / 3, kkl = s3 - p * 3;
            run_task(p * KKT + pass * 3 + kkl, p, kkl, c8);
        }
        __syncthreads();
        // GEMM: kb = pass*6 .. pass*6+5, both pixel groups share the B fragment
        #pragma unroll
        for (int j = 0; j < 6; ++j) {
            const int kb = pass * 6 + j;
            const int ew = (j * 32 + lg * 8) ^ ((lr & 7) << 3);
            const bf16x8 bf = *(const bf16x8*)(bsrc + (size_t)kb * 2048);
            const bf16x8 a0 = *(const bf16x8*)&s_vals[lr * KH3 + ew];
            const bf16x8 a1 = *(const bf16x8*)&s_vals[(16 + lr) * KH3 + ew];
            acc0 = __builtin_amdgcn_mfma_f32_16x16x32_bf16(a0, bf, acc0, 0, 0, 0);
            acc1 = __builtin_amdgcn_mfma_f32_16x16x32_bf16(a1, bf, acc1, 0, 0, 0);
        }
        if (pass < 2) __syncthreads();
    }

    const int cout = wid * 16 + lr;
    const size_t ob0 = (((size_t)b * COUT + cout) * HH + r0) * WW + wbase + lg * 4;
    *(f32x4*)&out[ob0]      = acc0;   // row r0,   pixels lg*4..lg*4+3
    *(f32x4*)&out[ob0 + WW] = acc1;   // row r0+1
}

extern "C" void kernel_launch(void* const* d_in, const int* in_sizes, int n_in,
                              void* d_out, int out_size, void* d_ws, size_t ws_size,
                              hipStream_t stream) {
    const float* x     = (const float*)d_in[0];
    const float* w_off = (const float*)d_in[1];
    const float* b_off = (const float*)d_in[2];
    const float* w_dcn = (const float*)d_in[3];
    float* out = (float*)d_out;

    prep_w<<<216, 256, 0, stream>>>(w_dcn, w_off);

    const int nblocks = BATCH * (HH / 2) * (WW / PIX);   // 4096
    deform_fused<<<nblocks, 256, 0, stream>>>(x, b_off, out);
}